// Round 6
// baseline (163.788 us; speedup 1.0000x reference)
//
#include <hip/hip_runtime.h>
#include <hip/hip_bf16.h>

// Relative (Music-Transformer) causal attention, MI355X gfx950.
// logit[i,j] = q_i·k_j + q_i·Erel[L-1-i+j] + key_len_add[j]; causal softmax; ·V
// fp32 in / fp32 out. Swapped-operand 16x16x32 bf16 MFMA ([key][q] layout),
// cross-tile register prefetch (software pipelining), KV-split x2 + combine.

typedef __attribute__((ext_vector_type(8))) short bf16x8;
typedef __attribute__((ext_vector_type(4))) float f32x4;
typedef unsigned short u16;

#define L_Q 2048
#define S_K 2048
#define N_H 8
#define E_D 64
#define RSTRIDE 512
#define LOG2E 1.44269504088896f

// ws byte offsets
#define QW_OFF 0u
#define KW_OFF (4u << 20)
#define VT_OFF (8u << 20)
#define EW_OFF (12u << 20)          // padded to 2176 rows; rows >=2048 = poison (safe: masked-only)
#define ML_OFF (13u << 20)
#define OW_OFF (14u << 20)
#define WS_PACK ((size_t)(13u << 20))
#define WS_FULL ((size_t)(14u << 20) + (size_t)4096 * 4096)

static __device__ __forceinline__ short f2bf(float f) {
  unsigned u = __builtin_bit_cast(unsigned, f);
  u += 0x7fffu + ((u >> 16) & 1u);   // RNE
  return (short)(u >> 16);
}

static __device__ __forceinline__ unsigned pk2(float a, float b) {
  return (unsigned)(u16)f2bf(a) | ((unsigned)(u16)f2bf(b) << 16);
}

static __device__ __forceinline__ bf16x8 loadpack8(const float* __restrict__ p, float scale) {
  float4 a = *reinterpret_cast<const float4*>(p);
  float4 b = *reinterpret_cast<const float4*>(p + 4);
  bf16x8 r;
  r[0] = f2bf(a.x * scale); r[1] = f2bf(a.y * scale);
  r[2] = f2bf(a.z * scale); r[3] = f2bf(a.w * scale);
  r[4] = f2bf(b.x * scale); r[5] = f2bf(b.y * scale);
  r[6] = f2bf(b.z * scale); r[7] = f2bf(b.w * scale);
  return r;
}

// ---- prep: Q (scaled by 1/8*log2e) & K -> bf16 [nh][seq][e]; Erel -> bf16 ----
__global__ __launch_bounds__(256)
void pack_qke(const float* __restrict__ Qf, const float* __restrict__ Kf,
              const float* __restrict__ Ef, u16* __restrict__ Qw,
              u16* __restrict__ Kw, u16* __restrict__ Ew) {
  const unsigned u = blockIdx.x * 256 + threadIdx.x;   // one float4 per thread
  if (u < 1048576u) {
    const unsigned v  = u & 524287u;
    const int e  = (v & 15) * 4;
    const int i  = (v >> 4) & 2047;
    const int nh = v >> 15;
    const int n = nh >> 3, h = nh & 7;
    const size_t src = ((size_t)(n * L_Q + i) * N_H + h) * E_D + e;
    const size_t dst = ((size_t)nh * L_Q + i) * E_D + e;
    const bool isQ = u < 524288u;
    float4 x = *reinterpret_cast<const float4*>((isQ ? Qf : Kf) + src);
    const float s = isQ ? 0.125f * LOG2E : 1.0f;
    ushort4 o;
    o.x = (u16)f2bf(x.x * s); o.y = (u16)f2bf(x.y * s);
    o.z = (u16)f2bf(x.z * s); o.w = (u16)f2bf(x.w * s);
    *reinterpret_cast<ushort4*>((isQ ? Qw : Kw) + dst) = o;
  } else {
    const unsigned v = u - 1048576u;                    // Erel
    if (v < 32768u) {
      const size_t idx = (size_t)v * 4;
      float4 x = *reinterpret_cast<const float4*>(Ef + idx);
      ushort4 o;
      o.x = (u16)f2bf(x.x); o.y = (u16)f2bf(x.y);
      o.z = (u16)f2bf(x.z); o.w = (u16)f2bf(x.w);
      *reinterpret_cast<ushort4*>(Ew + idx) = o;
    }
  }
}

// ---- prep: V -> bf16 transposed [nh][d][j] ----
__global__ __launch_bounds__(256)
void pack_vt(const float* __restrict__ Vf, u16* __restrict__ Vtw) {
  __shared__ u16 t[64][72];
  const int j0 = blockIdx.x * 64;
  const int nh = blockIdx.y;
  const int n = nh >> 3, h = nh & 7;
  const int tid = threadIdx.x;
  {
    const int jr = tid >> 2, dg = (tid & 3) * 16;
    const float* src = Vf + ((size_t)(n * L_Q + j0 + jr) * N_H + h) * E_D + dg;
#pragma unroll
    for (int q = 0; q < 4; ++q) {
      float4 x = *reinterpret_cast<const float4*>(src + q * 4);
      t[jr][dg + q * 4 + 0] = (u16)f2bf(x.x);
      t[jr][dg + q * 4 + 1] = (u16)f2bf(x.y);
      t[jr][dg + q * 4 + 2] = (u16)f2bf(x.z);
      t[jr][dg + q * 4 + 3] = (u16)f2bf(x.w);
    }
  }
  __syncthreads();
  {
    const int dr = tid >> 2, jg = (tid & 3) * 16;
    u16 tmp[16];
#pragma unroll
    for (int jj = 0; jj < 16; ++jj) tmp[jj] = t[jg + jj][dr];
    u16* dst = Vtw + ((size_t)nh * E_D + dr) * S_K + j0 + jg;
    *reinterpret_cast<uint4*>(dst)     = *reinterpret_cast<uint4*>(&tmp[0]);
    *reinterpret_cast<uint4*>(dst + 8) = *reinterpret_cast<uint4*>(&tmp[8]);
  }
}

// ---- main: swapped layout, cross-tile register prefetch, 1 wave/block ----
template <bool SPLIT>
__global__ __launch_bounds__(64, 2)
void relattn_p(const u16* __restrict__ Qw, const u16* __restrict__ Kw,
               const u16* __restrict__ Vtw, const u16* __restrict__ Ew,
               const float* __restrict__ KLp, float* __restrict__ Op,
               float* __restrict__ OwP, float* __restrict__ MLp) {
  const int bid = blockIdx.x;
  const int nh = bid & 15;               // head -> fixed XCD
  const int n = nh >> 3, h = nh & 7;
  const int rest = bid >> 4;
  const int wq = 127 - (SPLIT ? (rest >> 1) : rest);   // LPT
  const int sp = SPLIT ? (rest & 1) : 0;
  const int iw = wq * 16;
  const int lane = threadIdx.x;
  const int lo = lane & 15, hi = lane >> 4;
  const int nt = (wq >> 2) + 1;
  const int t0 = (SPLIT && sp) ? (nt >> 1) : 0;
  const int t1 = SPLIT ? (sp ? nt : (nt >> 1)) : nt;
  const int pairIdx = (iw + nh) * 2 + sp;

  __shared__ float qe_lds[16 * 84];

  if (SPLIT && t0 >= t1) {               // empty split: neutral partials
    f32x4* OwF = reinterpret_cast<f32x4*>(OwP) + (size_t)pairIdx * 256;
    f32x4 z = {};
#pragma unroll
    for (int dt = 0; dt < 4; ++dt) OwF[dt * 64 + lane] = z;
    if (lane < 16) { MLp[pairIdx * 32 + lane] = -1e30f; MLp[pairIdx * 32 + 16 + lane] = 0.f; }
    return;
  }

  // per-lane base pointers (loop-invariant)
  const u16* kpl = Kw + (size_t)nh * S_K * E_D + lo * E_D + hi * 8;
  const u16* epl = Ew + (size_t)(2032 - iw) * E_D + lo * E_D + hi * 8;  // + (j0+tt*16)*64 + kt*32
  const u16* vpl = Vtw + ((size_t)nh * E_D + lo) * S_K + 4 * hi;        // + dt*16*S_K + j0 + kt*32
  const float* klq = KLp + (size_t)n * S_K + 4 * hi;                    // + j0 + ct*16

  bf16x8 qa[2];
  {
    const u16* qrow = Qw + ((size_t)nh * L_Q + iw + lo) * E_D + hi * 8;
    qa[0] = *reinterpret_cast<const bf16x8*>(qrow);
    qa[1] = *reinterpret_cast<const bf16x8*>(qrow + 32);
  }

  bf16x8 kf[8], ef[10];
  ushort4 va[8], vb[8];
  float4 klv[4];

#define PREF_K(J0) { _Pragma("unroll") for (int kt = 0; kt < 2; ++kt) \
    _Pragma("unroll") for (int ct = 0; ct < 4; ++ct) \
      kf[kt * 4 + ct] = *reinterpret_cast<const bf16x8*>(kpl + (size_t)((J0) + ct * 16) * E_D + kt * 32); }
#define PREF_E(J0) { _Pragma("unroll") for (int kt = 0; kt < 2; ++kt) \
    _Pragma("unroll") for (int tt = 0; tt < 5; ++tt) \
      ef[kt * 5 + tt] = *reinterpret_cast<const bf16x8*>(epl + (size_t)((J0) + tt * 16) * E_D + kt * 32); }
#define PREF_V(J0) { _Pragma("unroll") for (int kt = 0; kt < 2; ++kt) \
    _Pragma("unroll") for (int dt = 0; dt < 4; ++dt) { \
      const u16* vp = vpl + (size_t)dt * 16 * S_K + (J0) + kt * 32; \
      va[kt * 4 + dt] = *reinterpret_cast<const ushort4*>(vp); \
      vb[kt * 4 + dt] = *reinterpret_cast<const ushort4*>(vp + 16); } }
#define PREF_KL(J0) { _Pragma("unroll") for (int ct = 0; ct < 4; ++ct) \
      klv[ct] = *reinterpret_cast<const float4*>(klq + (J0) + ct * 16); }

  PREF_K(t0 * 64)
  PREF_E(t0 * 64)
  PREF_V(t0 * 64)
  PREF_KL(t0 * 64)

  f32x4 o_acc[4] = {};
  float m_run = -1e30f, l_run = 0.f;
  const float* rb = &qe_lds[lo * 84 + (15 - lo) + 4 * hi];

  for (int t = t0; t < t1; ++t) {
    const int j0 = t * 64;
    const int jn = ((t + 1 < t1) ? t + 1 : t) * 64;   // last iter: harmless re-read

    // ---- QK^T + QE (MFMA cluster; operands prefetched last iteration) ----
    __builtin_amdgcn_s_setprio(1);
    f32x4 s_acc[4] = {};
#pragma unroll
    for (int kt = 0; kt < 2; ++kt)
#pragma unroll
      for (int ct = 0; ct < 4; ++ct)
        s_acc[ct] = __builtin_amdgcn_mfma_f32_16x16x32_bf16(kf[kt * 4 + ct], qa[kt], s_acc[ct], 0, 0, 0);
    f32x4 qe_acc[5] = {};
#pragma unroll
    for (int kt = 0; kt < 2; ++kt)
#pragma unroll
      for (int tt = 0; tt < 5; ++tt)
        qe_acc[tt] = __builtin_amdgcn_mfma_f32_16x16x32_bf16(ef[kt * 5 + tt], qa[kt], qe_acc[tt], 0, 0, 0);
    __builtin_amdgcn_s_setprio(0);

    // ---- spill QE to LDS for the skew gather ----
#pragma unroll
    for (int tt = 0; tt < 5; ++tt)
      *reinterpret_cast<f32x4*>(&qe_lds[lo * 84 + tt * 16 + 4 * hi]) = qe_acc[tt];

    // ---- prefetch next tile's K/E while the LDS writes drain ----
    PREF_K(jn)
    PREF_E(jn)

    // ---- logits: QK + rel (u = key - q + 15) + key_len*log2e; causal mask ----
    const bool maskt = (t == nt - 1);
    const int thr = iw + lo - j0 - 4 * hi;     // mask iff ct*16+g > thr
    float p[4][4];
#pragma unroll
    for (int ct = 0; ct < 4; ++ct) {
      const float k0 = klv[ct].x * LOG2E, k1 = klv[ct].y * LOG2E;
      const float k2 = klv[ct].z * LOG2E, k3 = klv[ct].w * LOG2E;
      p[ct][0] = s_acc[ct][0] + rb[ct * 16 + 0] + k0;
      p[ct][1] = s_acc[ct][1] + rb[ct * 16 + 1] + k1;
      p[ct][2] = s_acc[ct][2] + rb[ct * 16 + 2] + k2;
      p[ct][3] = s_acc[ct][3] + rb[ct * 16 + 3] + k3;
      if (maskt) {
#pragma unroll
        for (int g = 0; g < 4; ++g)
          if (ct * 16 + g > thr) p[ct][g] = -1e30f;
      }
    }

    // ---- online softmax (tree reductions; stats shared across 16-lane groups) ----
    float a0 = fmaxf(fmaxf(p[0][0], p[0][1]), fmaxf(p[0][2], p[0][3]));
    float a1 = fmaxf(fmaxf(p[1][0], p[1][1]), fmaxf(p[1][2], p[1][3]));
    float a2 = fmaxf(fmaxf(p[2][0], p[2][1]), fmaxf(p[2][2], p[2][3]));
    float a3 = fmaxf(fmaxf(p[3][0], p[3][1]), fmaxf(p[3][2], p[3][3]));
    float tmax = fmaxf(fmaxf(a0, a1), fmaxf(a2, a3));
    tmax = fmaxf(tmax, __shfl_xor(tmax, 16));
    tmax = fmaxf(tmax, __shfl_xor(tmax, 32));
    const float mnew = fmaxf(m_run, tmax);
    const float alpha = exp2f(m_run - mnew);
#pragma unroll
    for (int ct = 0; ct < 4; ++ct)
#pragma unroll
      for (int g = 0; g < 4; ++g)
        p[ct][g] = exp2f(p[ct][g] - mnew);
    float s0 = (p[0][0] + p[0][1]) + (p[0][2] + p[0][3]);
    float s1 = (p[1][0] + p[1][1]) + (p[1][2] + p[1][3]);
    float s2 = (p[2][0] + p[2][1]) + (p[2][2] + p[2][3]);
    float s3 = (p[3][0] + p[3][1]) + (p[3][2] + p[3][3]);
    float rs = (s0 + s1) + (s2 + s3);
    rs += __shfl_xor(rs, 16);
    rs += __shfl_xor(rs, 32);
    l_run = l_run * alpha + rs;
    m_run = mnew;

    PREF_KL(jn)

#pragma unroll
    for (int dt = 0; dt < 4; ++dt) o_acc[dt] = o_acc[dt] * alpha;

    // ---- pack P to bf16 ----
    uint4 w0, w1;
    w0.x = pk2(p[0][0], p[0][1]); w0.y = pk2(p[0][2], p[0][3]);
    w0.z = pk2(p[1][0], p[1][1]); w0.w = pk2(p[1][2], p[1][3]);
    w1.x = pk2(p[2][0], p[2][1]); w1.y = pk2(p[2][2], p[2][3]);
    w1.z = pk2(p[3][0], p[3][1]); w1.w = pk2(p[3][2], p[3][3]);
    const bf16x8 pb0 = __builtin_bit_cast(bf16x8, w0);
    const bf16x8 pb1 = __builtin_bit_cast(bf16x8, w1);

    // ---- PV (V prefetched last iteration) ----
    __builtin_amdgcn_s_setprio(1);
#pragma unroll
    for (int kt = 0; kt < 2; ++kt)
#pragma unroll
      for (int dt = 0; dt < 4; ++dt) {
        const uint2 ua = __builtin_bit_cast(uint2, va[kt * 4 + dt]);
        const uint2 ub = __builtin_bit_cast(uint2, vb[kt * 4 + dt]);
        uint4 uw; uw.x = ua.x; uw.y = ua.y; uw.z = ub.x; uw.w = ub.y;
        const bf16x8 vf = __builtin_bit_cast(bf16x8, uw);
        o_acc[dt] = __builtin_amdgcn_mfma_f32_16x16x32_bf16(vf, kt ? pb1 : pb0, o_acc[dt], 0, 0, 0);
      }
    __builtin_amdgcn_s_setprio(0);

    PREF_V(jn)
  }
#undef PREF_K
#undef PREF_E
#undef PREF_V
#undef PREF_KL

  if (SPLIT) {
    f32x4* OwF = reinterpret_cast<f32x4*>(OwP) + (size_t)pairIdx * 256;
#pragma unroll
    for (int dt = 0; dt < 4; ++dt) OwF[dt * 64 + lane] = o_acc[dt];
    if (lane < 16) { MLp[pairIdx * 32 + lane] = m_run; MLp[pairIdx * 32 + 16 + lane] = l_run; }
  } else {
    const float inv = 1.f / l_run;
    float* ob = Op + (size_t)n * L_Q * RSTRIDE + h * E_D + (size_t)(iw + lo) * RSTRIDE;
#pragma unroll
    for (int dt = 0; dt < 4; ++dt) {
      f32x4 o = o_acc[dt] * inv;
      *reinterpret_cast<f32x4*>(ob + dt * 16 + 4 * hi) = o;
    }
  }
}

// ---- combine the two KV-split partials ----
__global__ __launch_bounds__(64)
void combine2(const float* __restrict__ OwP, const float* __restrict__ MLp,
              float* __restrict__ Op) {
  const int pair = blockIdx.x;           // wq*16 + nh
  const int nh = pair & 15;
  const int wq = pair >> 4;
  const int n = nh >> 3, h = nh & 7;
  const int lane = threadIdx.x;
  const int lo = lane & 15, hi = lane >> 4;
  const int i0 = pair * 2, i1 = i0 + 1;
  const float m0 = MLp[i0 * 32 + lo], l0 = MLp[i0 * 32 + 16 + lo];
  const float m1 = MLp[i1 * 32 + lo], l1 = MLp[i1 * 32 + 16 + lo];
  const float M  = fmaxf(m0, m1);
  const float w0 = exp2f(m0 - M), w1 = exp2f(m1 - M);
  const float inv = 1.f / (l0 * w0 + l1 * w1);
  const f32x4* A = reinterpret_cast<const f32x4*>(OwP) + (size_t)i0 * 256;
  const f32x4* B = reinterpret_cast<const f32x4*>(OwP) + (size_t)i1 * 256;
  float* ob = Op + (size_t)n * L_Q * RSTRIDE + h * E_D + (size_t)(wq * 16 + lo) * RSTRIDE;
#pragma unroll
  for (int dt = 0; dt < 4; ++dt) {
    f32x4 a = A[dt * 64 + lane], b = B[dt * 64 + lane];
    f32x4 o = (a * w0 + b * w1) * inv;
    *reinterpret_cast<f32x4*>(ob + dt * 16 + 4 * hi) = o;
  }
}

// ---- fallback (no workspace): R3's verified non-packed kernel ----
__global__ __launch_bounds__(64, 2)
void relattn_fb(const float* __restrict__ Qf, const float* __restrict__ Kf,
                const float* __restrict__ Vf, const float* __restrict__ Ef,
                const float* __restrict__ KLp, float* __restrict__ Op) {
  const int bid = blockIdx.x;
  const int nh = bid & 15;
  const int n = nh >> 3, h = nh & 7;
  const int wq = 127 - (bid >> 4);
  const int iw = wq * 16;
  const int lane = threadIdx.x & 63;
  const int lo = lane & 15, hi = lane >> 4;

  __shared__ u16 p_lds[16 * 72];

  const float* klp = KLp + (size_t)n * S_K;
  float* ob = Op + (size_t)n * L_Q * RSTRIDE + h * E_D;

  bf16x8 qa[2];
  const float* qb = Qf + ((size_t)(n * L_Q + iw + lo) * N_H + h) * E_D + hi * 8;
  qa[0] = loadpack8(qb, 0.125f);
  qa[1] = loadpack8(qb + 32, 0.125f);

  f32x4 o_acc[4] = {};
  float m_run[4], l_run[4];
#pragma unroll
  for (int g = 0; g < 4; ++g) { m_run[g] = -1e30f; l_run[g] = 0.f; }

  const int ntiles = (wq >> 2) + 1;
  for (int t = 0; t < ntiles; ++t) {
    const int j0 = t * 64;
    f32x4 s_acc[4] = {};
#pragma unroll
    for (int kt = 0; kt < 2; ++kt)
#pragma unroll
      for (int ct = 0; ct < 4; ++ct) {
        bf16x8 kf = loadpack8(Kf + ((size_t)(n * S_K + j0 + ct * 16 + lo) * N_H + h) * E_D
                                  + kt * 32 + hi * 8, 1.f);
        s_acc[ct] = __builtin_amdgcn_mfma_f32_16x16x32_bf16(qa[kt], kf, s_acc[ct], 0, 0, 0);
      }
    const int mbase = (L_Q - 1) - (iw + 15) + j0;
    f32x4 qe_acc[5] = {};
#pragma unroll
    for (int kt = 0; kt < 2; ++kt)
#pragma unroll
      for (int tt = 0; tt < 5; ++tt) {
        int mr = mbase + tt * 16 + lo;
        mr = mr > (L_Q - 1) ? (L_Q - 1) : mr;
        bf16x8 ef = loadpack8(Ef + (size_t)mr * E_D + kt * 32 + hi * 8, 1.f);
        qe_acc[tt] = __builtin_amdgcn_mfma_f32_16x16x32_bf16(qa[kt], ef, qe_acc[tt], 0, 0, 0);
      }
    float kladd[4];
#pragma unroll
    for (int ct = 0; ct < 4; ++ct) kladd[ct] = klp[j0 + ct * 16 + lo];
    float sv[4][4];
#pragma unroll
    for (int ct = 0; ct < 4; ++ct) {
      const int jj = ct * 16 + lo;
#pragma unroll
      for (int g = 0; g < 4; ++g) {
        const int r = 4 * hi + g;
        const int u = jj - r + 15;
        const int srcl = (u & 15) | (hi << 4);
        const float a = __shfl(qe_acc[ct][g], srcl);
        const float b = __shfl(qe_acc[ct + 1][g], srcl);
        const float rel = (lo <= r) ? a : b;
        float s = s_acc[ct][g] + rel + kladd[ct];
        if (j0 + jj > iw + r) s = -1e9f;
        sv[ct][g] = s;
      }
    }
    float alpha[4];
#pragma unroll
    for (int g = 0; g < 4; ++g) {
      float mx = fmaxf(fmaxf(sv[0][g], sv[1][g]), fmaxf(sv[2][g], sv[3][g]));
      mx = fmaxf(mx, __shfl_xor(mx, 1));
      mx = fmaxf(mx, __shfl_xor(mx, 2));
      mx = fmaxf(mx, __shfl_xor(mx, 4));
      mx = fmaxf(mx, __shfl_xor(mx, 8));
      const float mnew = fmaxf(m_run[g], mx);
      const float al = __expf(m_run[g] - mnew);
      float rsv = 0.f;
#pragma unroll
      for (int ct = 0; ct < 4; ++ct) {
        const float pv = __expf(sv[ct][g] - mnew);
        sv[ct][g] = pv;
        rsv += pv;
      }
      rsv += __shfl_xor(rsv, 1);
      rsv += __shfl_xor(rsv, 2);
      rsv += __shfl_xor(rsv, 4);
      rsv += __shfl_xor(rsv, 8);
      l_run[g] = l_run[g] * al + rsv;
      m_run[g] = mnew;
      alpha[g] = al;
    }
#pragma unroll
    for (int dt = 0; dt < 4; ++dt)
#pragma unroll
      for (int g = 0; g < 4; ++g)
        o_acc[dt][g] *= alpha[g];
#pragma unroll
    for (int ct = 0; ct < 4; ++ct)
#pragma unroll
      for (int g = 0; g < 4; ++g)
        p_lds[(4 * hi + g) * 72 + ct * 16 + lo] = (u16)f2bf(sv[ct][g]);
#pragma unroll
    for (int jt = 0; jt < 2; ++jt) {
      const bf16x8 pav = *reinterpret_cast<const bf16x8*>(&p_lds[lo * 72 + jt * 32 + hi * 8]);
#pragma unroll
      for (int dt = 0; dt < 4; ++dt) {
        bf16x8 vf;
        const float* vp = Vf + ((size_t)(n * S_K + j0 + jt * 32 + hi * 8) * N_H + h) * E_D
                            + dt * 16 + lo;
#pragma unroll
        for (int e = 0; e < 8; ++e) vf[e] = f2bf(vp[(size_t)e * RSTRIDE]);
        o_acc[dt] = __builtin_amdgcn_mfma_f32_16x16x32_bf16(pav, vf, o_acc[dt], 0, 0, 0);
      }
    }
  }
  float inv[4];
#pragma unroll
  for (int g = 0; g < 4; ++g) inv[g] = 1.f / l_run[g];
#pragma unroll
  for (int dt = 0; dt < 4; ++dt)
#pragma unroll
    for (int g = 0; g < 4; ++g)
      ob[(size_t)(iw + 4 * hi + g) * RSTRIDE + dt * 16 + lo] = o_acc[dt][g] * inv[g];
}

extern "C" void kernel_launch(void* const* d_in, const int* in_sizes, int n_in,
                              void* d_out, int out_size, void* d_ws, size_t ws_size,
                              hipStream_t stream) {
  const float* Q  = (const float*)d_in[0];
  const float* K  = (const float*)d_in[1];
  const float* V  = (const float*)d_in[2];
  const float* E  = (const float*)d_in[3];
  // d_in[4] = attn_mask_add: exactly the causal 0/-1e9 mask -> applied structurally
  const float* KL = (const float*)d_in[5];
  float* O = (float*)d_out;

  char* ws = (char*)d_ws;
  u16* Qw   = (u16*)(ws + QW_OFF);
  u16* Kw   = (u16*)(ws + KW_OFF);
  u16* Vtw  = (u16*)(ws + VT_OFF);
  u16* Ew   = (u16*)(ws + EW_OFF);
  float* ML = (float*)(ws + ML_OFF);
  float* Ow = (float*)(ws + OW_OFF);

  const bool ws_pack = ws_size >= WS_PACK;
  const bool ws_full = ws_size >= WS_FULL;

  if (ws_pack) {
    hipLaunchKernelGGL(pack_qke, dim3((1048576 + 32768 + 255) / 256), dim3(256), 0, stream,
                       Q, K, E, Qw, Kw, Ew);
    hipLaunchKernelGGL(pack_vt, dim3(32, 16), dim3(256), 0, stream, V, Vtw);
  }
  if (ws_full) {
    hipLaunchKernelGGL((relattn_p<true>), dim3(4096), dim3(64), 0, stream,
                       Qw, Kw, Vtw, Ew, KL, O, Ow, ML);
    hipLaunchKernelGGL(combine2, dim3(2048), dim3(64), 0, stream, Ow, ML, O);
  } else if (ws_pack) {
    hipLaunchKernelGGL((relattn_p<false>), dim3(2048), dim3(64), 0, stream,
                       Qw, Kw, Vtw, Ew, KL, O, Ow, ML);
  } else {
    hipLaunchKernelGGL(relattn_fb, dim3(2048), dim3(64), 0, stream, Q, K, V, E, KL, O);
  }
}

// Round 8
// 111.454 us; speedup vs baseline: 1.4696x; 1.4696x over previous
//
#include <hip/hip_runtime.h>
#include <hip/hip_bf16.h>

// Relative (Music-Transformer) causal attention, MI355X gfx950.
// logit[i,j] = q_i·k_j + q_i·Erel[L-1-i+j] + key_len_add[j]; causal softmax; ·V
// fp32 in / fp32 out. Swapped-operand 16x16x32 bf16 MFMA ([key][q] layout).
// R8: 4-wave blocks share K/V/E tiles via single-buffered padded LDS
// (2 barriers/tile); all per-wave math identical to the R6-verified kernel.

typedef __attribute__((ext_vector_type(8))) short bf16x8;
typedef __attribute__((ext_vector_type(4))) float f32x4;
typedef unsigned short u16;

#define L_Q 2048
#define S_K 2048
#define N_H 8
#define E_D 64
#define RSTRIDE 512
#define LOG2E 1.44269504088896f

// ws byte offsets
#define QW_OFF 0u
#define KW_OFF (4u << 20)
#define VT_OFF (8u << 20)
#define EW_OFF (12u << 20)          // rows >=2048 unwritten; feed masked slots only
#define WS_PACK ((size_t)(13u << 20))

static __device__ __forceinline__ short f2bf(float f) {
  unsigned u = __builtin_bit_cast(unsigned, f);
  u += 0x7fffu + ((u >> 16) & 1u);   // RNE
  return (short)(u >> 16);
}

static __device__ __forceinline__ unsigned pk2(float a, float b) {
  return (unsigned)(u16)f2bf(a) | ((unsigned)(u16)f2bf(b) << 16);
}

static __device__ __forceinline__ bf16x8 loadpack8(const float* __restrict__ p, float scale) {
  float4 a = *reinterpret_cast<const float4*>(p);
  float4 b = *reinterpret_cast<const float4*>(p + 4);
  bf16x8 r;
  r[0] = f2bf(a.x * scale); r[1] = f2bf(a.y * scale);
  r[2] = f2bf(a.z * scale); r[3] = f2bf(a.w * scale);
  r[4] = f2bf(b.x * scale); r[5] = f2bf(b.y * scale);
  r[6] = f2bf(b.z * scale); r[7] = f2bf(b.w * scale);
  return r;
}

// ---- prep: Q (scaled by 1/8*log2e) & K -> bf16 [nh][seq][e]; Erel -> bf16 ----
__global__ __launch_bounds__(256)
void pack_qke(const float* __restrict__ Qf, const float* __restrict__ Kf,
              const float* __restrict__ Ef, u16* __restrict__ Qw,
              u16* __restrict__ Kw, u16* __restrict__ Ew) {
  const unsigned u = blockIdx.x * 256 + threadIdx.x;   // one float4 per thread
  if (u < 1048576u) {
    const unsigned v  = u & 524287u;
    const int e  = (v & 15) * 4;
    const int i  = (v >> 4) & 2047;
    const int nh = v >> 15;
    const int n = nh >> 3, h = nh & 7;
    const size_t src = ((size_t)(n * L_Q + i) * N_H + h) * E_D + e;
    const size_t dst = ((size_t)nh * L_Q + i) * E_D + e;
    const bool isQ = u < 524288u;
    float4 x = *reinterpret_cast<const float4*>((isQ ? Qf : Kf) + src);
    const float s = isQ ? 0.125f * LOG2E : 1.0f;
    ushort4 o;
    o.x = (u16)f2bf(x.x * s); o.y = (u16)f2bf(x.y * s);
    o.z = (u16)f2bf(x.z * s); o.w = (u16)f2bf(x.w * s);
    *reinterpret_cast<ushort4*>((isQ ? Qw : Kw) + dst) = o;
  } else {
    const unsigned v = u - 1048576u;                    // Erel
    if (v < 32768u) {
      const size_t idx = (size_t)v * 4;
      float4 x = *reinterpret_cast<const float4*>(Ef + idx);
      ushort4 o;
      o.x = (u16)f2bf(x.x); o.y = (u16)f2bf(x.y);
      o.z = (u16)f2bf(x.z); o.w = (u16)f2bf(x.w);
      *reinterpret_cast<ushort4*>(Ew + idx) = o;
    }
  }
}

// ---- prep: V -> bf16 transposed [nh][d][j] ----
__global__ __launch_bounds__(256)
void pack_vt(const float* __restrict__ Vf, u16* __restrict__ Vtw) {
  __shared__ u16 t[64][72];
  const int j0 = blockIdx.x * 64;
  const int nh = blockIdx.y;
  const int n = nh >> 3, h = nh & 7;
  const int tid = threadIdx.x;
  {
    const int jr = tid >> 2, dg = (tid & 3) * 16;
    const float* src = Vf + ((size_t)(n * L_Q + j0 + jr) * N_H + h) * E_D + dg;
#pragma unroll
    for (int q = 0; q < 4; ++q) {
      float4 x = *reinterpret_cast<const float4*>(src + q * 4);
      t[jr][dg + q * 4 + 0] = (u16)f2bf(x.x);
      t[jr][dg + q * 4 + 1] = (u16)f2bf(x.y);
      t[jr][dg + q * 4 + 2] = (u16)f2bf(x.z);
      t[jr][dg + q * 4 + 3] = (u16)f2bf(x.w);
    }
  }
  __syncthreads();
  {
    const int dr = tid >> 2, jg = (tid & 3) * 16;
    u16 tmp[16];
#pragma unroll
    for (int jj = 0; jj < 16; ++jj) tmp[jj] = t[jg + jj][dr];
    u16* dst = Vtw + ((size_t)nh * E_D + dr) * S_K + j0 + jg;
    *reinterpret_cast<uint4*>(dst)     = *reinterpret_cast<uint4*>(&tmp[0]);
    *reinterpret_cast<uint4*>(dst + 8) = *reinterpret_cast<uint4*>(&tmp[8]);
  }
}

// ---- main: 4 waves share K/V/E tiles via padded LDS; R6-verified wave math ----
__global__ __launch_bounds__(256, 2)
void relattn_sh(const u16* __restrict__ Qw, const u16* __restrict__ Kw,
                const u16* __restrict__ Vtw, const u16* __restrict__ Ew,
                const float* __restrict__ KLp, float* __restrict__ Op) {
  const int bid = blockIdx.x;
  const int nh = bid & 15;                 // head -> fixed XCD pattern
  const int n = nh >> 3, h = nh & 7;
  const int q16 = bid >> 4;                // 0..31
  const int wq64 = (q16 < 16) ? (31 - q16) : (q16 - 16);  // LPT pairing
  const int iw64 = wq64 * 64;
  const int tid = threadIdx.x;
  const int wid = tid >> 6;
  const int lane = tid & 63;
  const int lo = lane & 15, hi = lane >> 4;
  const int iw = iw64 + wid * 16;          // this wave's first q-row
  const int nt = wq64 + 1;

  __shared__ u16 Kls[64 * 72];             // K tile  [j_local][e], pad 72
  __shared__ u16 Els[128 * 72];            // E band  [row_local][e], pad 72
  __shared__ u16 Vls[64 * 72];             // V^T tile [d][j_local], pad 72
  __shared__ float qe_lds[4][16 * 84];     // per-wave QE spill (R6 layout)

  const int Ebase = 1984 - iw64;           // abs padded-E row = Ebase + j0 + row_local

  const u16* Kg = Kw + (size_t)nh * S_K * E_D;
  const u16* Vg = Vtw + (size_t)nh * E_D * S_K;
  const float* klq = KLp + (size_t)n * S_K + 4 * hi;

  // staging lane coords: each row = 64 u16 = 8 chunks of 16B; lane -> (srow, scc)
  const int srow = lane >> 3;
  const int scc  = lane & 7;
  uint4 stK[2], stV[2], stE[4];

  auto LOADSTAGE = [&](int jj0) {          // linear global loads (issue-early)
#pragma unroll
    for (int i = 0; i < 2; ++i) {
      const int row = (wid + i * 4) * 8 + srow;          // 0..63
      stK[i] = *reinterpret_cast<const uint4*>(Kg + (size_t)(jj0 + row) * E_D + scc * 8);
      stV[i] = *reinterpret_cast<const uint4*>(Vg + (size_t)row * S_K + jj0 + scc * 8);
    }
#pragma unroll
    for (int i = 0; i < 4; ++i) {
      const int row = (wid + i * 4) * 8 + srow;          // 0..127
      stE[i] = *reinterpret_cast<const uint4*>(Ew + (size_t)(Ebase + jj0 + row) * E_D + scc * 8);
    }
  };
  auto WRITESTAGE = [&]() {                // padded LDS writes (no swizzle)
#pragma unroll
    for (int i = 0; i < 2; ++i) {
      const int row = (wid + i * 4) * 8 + srow;
      *reinterpret_cast<uint4*>(&Kls[row * 72 + scc * 8]) = stK[i];
      *reinterpret_cast<uint4*>(&Vls[row * 72 + scc * 8]) = stV[i];
    }
#pragma unroll
    for (int i = 0; i < 4; ++i) {
      const int row = (wid + i * 4) * 8 + srow;
      *reinterpret_cast<uint4*>(&Els[row * 72 + scc * 8]) = stE[i];
    }
  };

  // Q fragment (B operand): col=lo -> q-row iw+lo, k=hi*8+e (+32*kt)
  bf16x8 qa[2];
  {
    const u16* qrow = Qw + ((size_t)nh * L_Q + iw + lo) * E_D + hi * 8;
    qa[0] = *reinterpret_cast<const bf16x8*>(qrow);
    qa[1] = *reinterpret_cast<const bf16x8*>(qrow + 32);
  }

  f32x4 o_acc[4] = {};                     // [dt]: O^T rows d=dt*16+4hi+g, col q=lo
  float m_run = -1e30f, l_run = 0.f;
  const float* rb = &qe_lds[wid][lo * 84 + (15 - lo) + 4 * hi];   // R6 skew read base

  LOADSTAGE(0);

  for (int t = 0; t < nt; ++t) {
    const int j0 = t * 64;
    __syncthreads();                       // all waves done reading previous tile
    WRITESTAGE();                          // (compiler vmcnt-waits on st*)
    if (t + 1 < nt) LOADSTAGE(j0 + 64);    // issue next tile's global loads early
    __syncthreads();                       // tile t visible to all waves

    // ---- QK^T + QE band (MFMA cluster from LDS) ----
    __builtin_amdgcn_s_setprio(1);
    f32x4 s_acc[4] = {};
#pragma unroll
    for (int kt = 0; kt < 2; ++kt)
#pragma unroll
      for (int ct = 0; ct < 4; ++ct) {
        const bf16x8 kf = *reinterpret_cast<const bf16x8*>(
            &Kls[(ct * 16 + lo) * 72 + (kt * 4 + hi) * 8]);
        s_acc[ct] = __builtin_amdgcn_mfma_f32_16x16x32_bf16(kf, qa[kt], s_acc[ct], 0, 0, 0);
      }
    f32x4 qe_acc[5] = {};
#pragma unroll
    for (int kt = 0; kt < 2; ++kt)
#pragma unroll
      for (int tt = 0; tt < 5; ++tt) {
        const int erow = 48 - 16 * wid + tt * 16 + lo;   // 0..127
        const bf16x8 ef = *reinterpret_cast<const bf16x8*>(
            &Els[erow * 72 + (kt * 4 + hi) * 8]);
        qe_acc[tt] = __builtin_amdgcn_mfma_f32_16x16x32_bf16(ef, qa[kt], qe_acc[tt], 0, 0, 0);
      }
    __builtin_amdgcn_s_setprio(0);

    // ---- spill QE to per-wave LDS (f32, R6-verified layout) ----
#pragma unroll
    for (int tt = 0; tt < 5; ++tt)
      *reinterpret_cast<f32x4*>(&qe_lds[wid][lo * 84 + tt * 16 + 4 * hi]) = qe_acc[tt];

    float4 klv[4];
#pragma unroll
    for (int ct = 0; ct < 4; ++ct)
      klv[ct] = *reinterpret_cast<const float4*>(klq + j0 + ct * 16);

    // ---- logits: QK + rel (u = key - q + 15) + key_len*log2e; causal mask ----
    const bool maskt = (t == nt - 1);
    const int thr = iw + lo - j0 - 4 * hi;     // mask iff ct*16+g > thr
    float p[4][4];
#pragma unroll
    for (int ct = 0; ct < 4; ++ct) {
      const float k0 = klv[ct].x * LOG2E, k1 = klv[ct].y * LOG2E;
      const float k2 = klv[ct].z * LOG2E, k3 = klv[ct].w * LOG2E;
      p[ct][0] = s_acc[ct][0] + rb[ct * 16 + 0] + k0;
      p[ct][1] = s_acc[ct][1] + rb[ct * 16 + 1] + k1;
      p[ct][2] = s_acc[ct][2] + rb[ct * 16 + 2] + k2;
      p[ct][3] = s_acc[ct][3] + rb[ct * 16 + 3] + k3;
      if (maskt) {
#pragma unroll
        for (int g = 0; g < 4; ++g)
          if (ct * 16 + g > thr) p[ct][g] = -1e30f;
      }
    }

    // ---- online softmax (stats per q=lo, reduced across the 4 hi-groups) ----
    float a0 = fmaxf(fmaxf(p[0][0], p[0][1]), fmaxf(p[0][2], p[0][3]));
    float a1 = fmaxf(fmaxf(p[1][0], p[1][1]), fmaxf(p[1][2], p[1][3]));
    float a2 = fmaxf(fmaxf(p[2][0], p[2][1]), fmaxf(p[2][2], p[2][3]));
    float a3 = fmaxf(fmaxf(p[3][0], p[3][1]), fmaxf(p[3][2], p[3][3]));
    float tmax = fmaxf(fmaxf(a0, a1), fmaxf(a2, a3));
    tmax = fmaxf(tmax, __shfl_xor(tmax, 16));
    tmax = fmaxf(tmax, __shfl_xor(tmax, 32));
    const float mnew = fmaxf(m_run, tmax);
    const float alpha = exp2f(m_run - mnew);
#pragma unroll
    for (int ct = 0; ct < 4; ++ct)
#pragma unroll
      for (int g = 0; g < 4; ++g)
        p[ct][g] = exp2f(p[ct][g] - mnew);
    float s0 = (p[0][0] + p[0][1]) + (p[0][2] + p[0][3]);
    float s1 = (p[1][0] + p[1][1]) + (p[1][2] + p[1][3]);
    float s2 = (p[2][0] + p[2][1]) + (p[2][2] + p[2][3]);
    float s3 = (p[3][0] + p[3][1]) + (p[3][2] + p[3][3]);
    float rs = (s0 + s1) + (s2 + s3);
    rs += __shfl_xor(rs, 16);
    rs += __shfl_xor(rs, 32);
    l_run = l_run * alpha + rs;
    m_run = mnew;

#pragma unroll
    for (int dt = 0; dt < 4; ++dt) o_acc[dt] = o_acc[dt] * alpha;

    // ---- pack P to bf16 (k-perm: e<4 -> key 4hi+e; e>=4 -> key 16+4hi+e-4) ----
    uint4 w0, w1;
    w0.x = pk2(p[0][0], p[0][1]); w0.y = pk2(p[0][2], p[0][3]);
    w0.z = pk2(p[1][0], p[1][1]); w0.w = pk2(p[1][2], p[1][3]);
    w1.x = pk2(p[2][0], p[2][1]); w1.y = pk2(p[2][2], p[2][3]);
    w1.z = pk2(p[3][0], p[3][1]); w1.w = pk2(p[3][2], p[3][3]);
    const bf16x8 pb0 = __builtin_bit_cast(bf16x8, w0);
    const bf16x8 pb1 = __builtin_bit_cast(bf16x8, w1);

    // ---- PV from padded V^T LDS (same key mapping as R6) ----
    __builtin_amdgcn_s_setprio(1);
#pragma unroll
    for (int kt = 0; kt < 2; ++kt)
#pragma unroll
      for (int dt = 0; dt < 4; ++dt) {
        const int vrow = dt * 16 + lo;
        const int cbase = (kt * 4 + (hi >> 1)) * 8 + (hi & 1) * 4;
        const uint2 va2 = *reinterpret_cast<const uint2*>(&Vls[vrow * 72 + cbase]);
        const uint2 vb2 = *reinterpret_cast<const uint2*>(&Vls[vrow * 72 + cbase + 16]);
        uint4 uw; uw.x = va2.x; uw.y = va2.y; uw.z = vb2.x; uw.w = vb2.y;
        const bf16x8 vf = __builtin_bit_cast(bf16x8, uw);
        o_acc[dt] = __builtin_amdgcn_mfma_f32_16x16x32_bf16(vf, kt ? pb1 : pb0, o_acc[dt], 0, 0, 0);
      }
    __builtin_amdgcn_s_setprio(0);
  }

  // ---- epilogue ----
  const float inv = 1.f / l_run;
  float* ob = Op + (size_t)n * L_Q * RSTRIDE + h * E_D + (size_t)(iw + lo) * RSTRIDE;
#pragma unroll
  for (int dt = 0; dt < 4; ++dt) {
    f32x4 o = o_acc[dt] * inv;
    *reinterpret_cast<f32x4*>(ob + dt * 16 + 4 * hi) = o;
  }
}

// ---- fallback (no workspace): R3's verified non-packed kernel ----
__global__ __launch_bounds__(64, 2)
void relattn_fb(const float* __restrict__ Qf, const float* __restrict__ Kf,
                const float* __restrict__ Vf, const float* __restrict__ Ef,
                const float* __restrict__ KLp, float* __restrict__ Op) {
  const int bid = blockIdx.x;
  const int nh = bid & 15;
  const int n = nh >> 3, h = nh & 7;
  const int wq = 127 - (bid >> 4);
  const int iw = wq * 16;
  const int lane = threadIdx.x & 63;
  const int lo = lane & 15, hi = lane >> 4;

  __shared__ u16 p_lds[16 * 72];

  const float* klp = KLp + (size_t)n * S_K;
  float* ob = Op + (size_t)n * L_Q * RSTRIDE + h * E_D;

  bf16x8 qa[2];
  const float* qb = Qf + ((size_t)(n * L_Q + iw + lo) * N_H + h) * E_D + hi * 8;
  qa[0] = loadpack8(qb, 0.125f);
  qa[1] = loadpack8(qb + 32, 0.125f);

  f32x4 o_acc[4] = {};
  float m_run[4], l_run[4];
#pragma unroll
  for (int g = 0; g < 4; ++g) { m_run[g] = -1e30f; l_run[g] = 0.f; }

  const int ntiles = (wq >> 2) + 1;
  for (int t = 0; t < ntiles; ++t) {
    const int j0 = t * 64;
    f32x4 s_acc[4] = {};
#pragma unroll
    for (int kt = 0; kt < 2; ++kt)
#pragma unroll
      for (int ct = 0; ct < 4; ++ct) {
        bf16x8 kf = loadpack8(Kf + ((size_t)(n * S_K + j0 + ct * 16 + lo) * N_H + h) * E_D
                                  + kt * 32 + hi * 8, 1.f);
        s_acc[ct] = __builtin_amdgcn_mfma_f32_16x16x32_bf16(qa[kt], kf, s_acc[ct], 0, 0, 0);
      }
    const int mbase = (L_Q - 1) - (iw + 15) + j0;
    f32x4 qe_acc[5] = {};
#pragma unroll
    for (int kt = 0; kt < 2; ++kt)
#pragma unroll
      for (int tt = 0; tt < 5; ++tt) {
        int mr = mbase + tt * 16 + lo;
        mr = mr > (L_Q - 1) ? (L_Q - 1) : mr;
        bf16x8 ef = loadpack8(Ef + (size_t)mr * E_D + kt * 32 + hi * 8, 1.f);
        qe_acc[tt] = __builtin_amdgcn_mfma_f32_16x16x32_bf16(qa[kt], ef, qe_acc[tt], 0, 0, 0);
      }
    float kladd[4];
#pragma unroll
    for (int ct = 0; ct < 4; ++ct) kladd[ct] = klp[j0 + ct * 16 + lo];
    float sv[4][4];
#pragma unroll
    for (int ct = 0; ct < 4; ++ct) {
      const int jj = ct * 16 + lo;
#pragma unroll
      for (int g = 0; g < 4; ++g) {
        const int r = 4 * hi + g;
        const int u = jj - r + 15;
        const int srcl = (u & 15) | (hi << 4);
        const float a = __shfl(qe_acc[ct][g], srcl);
        const float bq = __shfl(qe_acc[ct + 1][g], srcl);
        const float rel = (lo <= r) ? a : bq;
        float s = s_acc[ct][g] + rel + kladd[ct];
        if (j0 + jj > iw + r) s = -1e9f;
        sv[ct][g] = s;
      }
    }
    float alpha[4];
#pragma unroll
    for (int g = 0; g < 4; ++g) {
      float mx = fmaxf(fmaxf(sv[0][g], sv[1][g]), fmaxf(sv[2][g], sv[3][g]));
      mx = fmaxf(mx, __shfl_xor(mx, 1));
      mx = fmaxf(mx, __shfl_xor(mx, 2));
      mx = fmaxf(mx, __shfl_xor(mx, 4));
      mx = fmaxf(mx, __shfl_xor(mx, 8));
      const float mnew = fmaxf(m_run[g], mx);
      const float al = __expf(m_run[g] - mnew);
      float rsv = 0.f;
#pragma unroll
      for (int ct = 0; ct < 4; ++ct) {
        const float pv = __expf(sv[ct][g] - mnew);
        sv[ct][g] = pv;
        rsv += pv;
      }
      rsv += __shfl_xor(rsv, 1);
      rsv += __shfl_xor(rsv, 2);
      rsv += __shfl_xor(rsv, 4);
      rsv += __shfl_xor(rsv, 8);
      l_run[g] = l_run[g] * al + rsv;
      m_run[g] = mnew;
      alpha[g] = al;
    }
#pragma unroll
    for (int dt = 0; dt < 4; ++dt)
#pragma unroll
      for (int g = 0; g < 4; ++g)
        o_acc[dt][g] *= alpha[g];
#pragma unroll
    for (int ct = 0; ct < 4; ++ct)
#pragma unroll
      for (int g = 0; g < 4; ++g)
        p_lds[(4 * hi + g) * 72 + ct * 16 + lo] = (u16)f2bf(sv[ct][g]);
#pragma unroll
    for (int jt = 0; jt < 2; ++jt) {
      const bf16x8 pav = *reinterpret_cast<const bf16x8*>(&p_lds[lo * 72 + jt * 32 + hi * 8]);
#pragma unroll
      for (int dt = 0; dt < 4; ++dt) {
        bf16x8 vf;
        const float* vp = Vf + ((size_t)(n * S_K + j0 + jt * 32 + hi * 8) * N_H + h) * E_D
                            + dt * 16 + lo;
#pragma unroll
        for (int e = 0; e < 8; ++e) vf[e] = f2bf(vp[(size_t)e * RSTRIDE]);
        o_acc[dt] = __builtin_amdgcn_mfma_f32_16x16x32_bf16(pav, vf, o_acc[dt], 0, 0, 0);
      }
    }
  }
  float inv[4];
#pragma unroll
  for (int g = 0; g < 4; ++g) inv[g] = 1.f / l_run[g];
#pragma unroll
  for (int dt = 0; dt < 4; ++dt)
#pragma unroll
    for (int g = 0; g < 4; ++g)
      ob[(size_t)(iw + 4 * hi + g) * RSTRIDE + dt * 16 + lo] = o_acc[dt][g] * inv[g];
}

extern "C" void kernel_launch(void* const* d_in, const int* in_sizes, int n_in,
                              void* d_out, int out_size, void* d_ws, size_t ws_size,
                              hipStream_t stream) {
  const float* Q  = (const float*)d_in[0];
  const float* K  = (const float*)d_in[1];
  const float* V  = (const float*)d_in[2];
  const float* E  = (const float*)d_in[3];
  // d_in[4] = attn_mask_add: exactly the causal 0/-1e9 mask -> applied structurally
  const float* KL = (const float*)d_in[5];
  float* O = (float*)d_out;

  char* ws = (char*)d_ws;
  u16* Qw   = (u16*)(ws + QW_OFF);
  u16* Kw   = (u16*)(ws + KW_OFF);
  u16* Vtw  = (u16*)(ws + VT_OFF);
  u16* Ew   = (u16*)(ws + EW_OFF);

  if (ws_size >= WS_PACK) {
    hipLaunchKernelGGL(pack_qke, dim3((1048576 + 32768 + 255) / 256), dim3(256), 0, stream,
                       Q, K, E, Qw, Kw, Ew);
    hipLaunchKernelGGL(pack_vt, dim3(32, 16), dim3(256), 0, stream, V, Vtw);
    hipLaunchKernelGGL(relattn_sh, dim3(512), dim3(256), 0, stream,
                       Qw, Kw, Vtw, Ew, KL, O);
  } else {
    hipLaunchKernelGGL(relattn_fb, dim3(2048), dim3(64), 0, stream, Q, K, V, E, KL, O);
  }
}

// Round 9
// 107.297 us; speedup vs baseline: 1.5265x; 1.0387x over previous
//
#include <hip/hip_runtime.h>
#include <hip/hip_bf16.h>

// Relative (Music-Transformer) causal attention, MI355X gfx950.
// logit[i,j] = q_i·k_j + q_i·Erel[L-1-i+j] + key_len_add[j]; causal softmax; ·V
// fp32 in / fp32 out. Swapped-operand 16x16x32 bf16 MFMA ([key][q] layout).
// R9: XOR-swizzled staging, K/V double-buffer + E 3-slot ring (1 barrier/tile),
// QE last-subtile carry. Per-wave math identical to the R8-verified kernel.

typedef __attribute__((ext_vector_type(8))) short bf16x8;
typedef __attribute__((ext_vector_type(4))) float f32x4;
typedef unsigned short u16;

#define L_Q 2048
#define S_K 2048
#define N_H 8
#define E_D 64
#define RSTRIDE 512
#define LOG2E 1.44269504088896f

#define QW_OFF 0u
#define KW_OFF (4u << 20)
#define VT_OFF (8u << 20)
#define EW_OFF (12u << 20)          // 1MB region; rows >=2048 unwritten -> masked slots only
#define WS_PACK ((size_t)(13u << 20))

static __device__ __forceinline__ short f2bf(float f) {
  unsigned u = __builtin_bit_cast(unsigned, f);
  u += 0x7fffu + ((u >> 16) & 1u);   // RNE
  return (short)(u >> 16);
}

static __device__ __forceinline__ unsigned pk2(float a, float b) {
  return (unsigned)(u16)f2bf(a) | ((unsigned)(u16)f2bf(b) << 16);
}

static __device__ __forceinline__ bf16x8 loadpack8(const float* __restrict__ p, float scale) {
  float4 a = *reinterpret_cast<const float4*>(p);
  float4 b = *reinterpret_cast<const float4*>(p + 4);
  bf16x8 r;
  r[0] = f2bf(a.x * scale); r[1] = f2bf(a.y * scale);
  r[2] = f2bf(a.z * scale); r[3] = f2bf(a.w * scale);
  r[4] = f2bf(b.x * scale); r[5] = f2bf(b.y * scale);
  r[6] = f2bf(b.z * scale); r[7] = f2bf(b.w * scale);
  return r;
}

// ---- prep: Q (scaled by 1/8*log2e) & K -> bf16 [nh][seq][e]; Erel -> bf16 ----
__global__ __launch_bounds__(256)
void pack_qke(const float* __restrict__ Qf, const float* __restrict__ Kf,
              const float* __restrict__ Ef, u16* __restrict__ Qw,
              u16* __restrict__ Kw, u16* __restrict__ Ew) {
  const unsigned u = blockIdx.x * 256 + threadIdx.x;   // one float4 per thread
  if (u < 1048576u) {
    const unsigned v  = u & 524287u;
    const int e  = (v & 15) * 4;
    const int i  = (v >> 4) & 2047;
    const int nh = v >> 15;
    const int n = nh >> 3, h = nh & 7;
    const size_t src = ((size_t)(n * L_Q + i) * N_H + h) * E_D + e;
    const size_t dst = ((size_t)nh * L_Q + i) * E_D + e;
    const bool isQ = u < 524288u;
    float4 x = *reinterpret_cast<const float4*>((isQ ? Qf : Kf) + src);
    const float s = isQ ? 0.125f * LOG2E : 1.0f;
    ushort4 o;
    o.x = (u16)f2bf(x.x * s); o.y = (u16)f2bf(x.y * s);
    o.z = (u16)f2bf(x.z * s); o.w = (u16)f2bf(x.w * s);
    *reinterpret_cast<ushort4*>((isQ ? Qw : Kw) + dst) = o;
  } else {
    const unsigned v = u - 1048576u;                    // Erel
    if (v < 32768u) {
      const size_t idx = (size_t)v * 4;
      float4 x = *reinterpret_cast<const float4*>(Ef + idx);
      ushort4 o;
      o.x = (u16)f2bf(x.x); o.y = (u16)f2bf(x.y);
      o.z = (u16)f2bf(x.z); o.w = (u16)f2bf(x.w);
      *reinterpret_cast<ushort4*>(Ew + idx) = o;
    }
  }
}

// ---- prep: V -> bf16 transposed [nh][d][j] ----
__global__ __launch_bounds__(256)
void pack_vt(const float* __restrict__ Vf, u16* __restrict__ Vtw) {
  __shared__ u16 t[64][72];
  const int j0 = blockIdx.x * 64;
  const int nh = blockIdx.y;
  const int n = nh >> 3, h = nh & 7;
  const int tid = threadIdx.x;
  {
    const int jr = tid >> 2, dg = (tid & 3) * 16;
    const float* src = Vf + ((size_t)(n * L_Q + j0 + jr) * N_H + h) * E_D + dg;
#pragma unroll
    for (int q = 0; q < 4; ++q) {
      float4 x = *reinterpret_cast<const float4*>(src + q * 4);
      t[jr][dg + q * 4 + 0] = (u16)f2bf(x.x);
      t[jr][dg + q * 4 + 1] = (u16)f2bf(x.y);
      t[jr][dg + q * 4 + 2] = (u16)f2bf(x.z);
      t[jr][dg + q * 4 + 3] = (u16)f2bf(x.w);
    }
  }
  __syncthreads();
  {
    const int dr = tid >> 2, jg = (tid & 3) * 16;
    u16 tmp[16];
#pragma unroll
    for (int jj = 0; jj < 16; ++jj) tmp[jj] = t[jg + jj][dr];
    u16* dst = Vtw + ((size_t)nh * E_D + dr) * S_K + j0 + jg;
    *reinterpret_cast<uint4*>(dst)     = *reinterpret_cast<uint4*>(&tmp[0]);
    *reinterpret_cast<uint4*>(dst + 8) = *reinterpret_cast<uint4*>(&tmp[8]);
  }
}

// ---- main: swizzled staging, K/V dbuf + E ring, 1 barrier/tile, QE carry ----
__global__ __launch_bounds__(256, 2)
void relattn_r9(const u16* __restrict__ Qw, const u16* __restrict__ Kw,
                const u16* __restrict__ Vtw, const u16* __restrict__ Ew,
                const float* __restrict__ KLp, float* __restrict__ Op) {
  const int bid = blockIdx.x;
  const int nh = bid & 15;                 // head -> fixed XCD pattern
  const int n = nh >> 3, h = nh & 7;
  const int q16 = bid >> 4;                // 0..31
  const int wq64 = (q16 < 16) ? (31 - q16) : (q16 - 16);  // LPT pairing
  const int iw64 = wq64 * 64;
  const int tid = threadIdx.x;
  const int wid = tid >> 6;
  const int lane = tid & 63;
  const int lo = lane & 15, hi = lane >> 4;
  const int iw = iw64 + wid * 16;          // this wave's first q-row
  const int nt = wq64 + 1;

  __shared__ u16 Kls[2][64 * 64];          // K tiles, swizzled (chunk ^= row&7)
  __shared__ u16 Vls[2][64 * 64];          // V^T tiles, swizzled
  __shared__ u16 Els[192 * 64];            // E ring: 3 slots x 64 rows, swizzled
  __shared__ float qe_lds[4][16 * 80];     // per-wave QE spill, stride 80

  const int Ebase = 1984 - iw64;           // abs padded-E row = Ebase + 64t + roff
  const u16* Kg = Kw + (size_t)nh * S_K * E_D;
  const u16* Vg = Vtw + (size_t)nh * E_D * S_K;
  const float* klq = KLp + (size_t)n * S_K + 4 * hi;

  // staging lane coords: rows r0/r1 (≡ srow mod 8), 16B chunk scc; swizzle const/thread
  const int srow = lane >> 3;
  const int scc  = lane & 7;
  const int r0 = wid * 8 + srow;           // 0..31
  const int r1 = r0 + 32;                  // 32..63
  const int swc = (scc ^ srow) * 8;        // swizzled chunk offset (u16 units)
  uint4 stK[2], stV[2], stE[2];

  auto LOAD_KV = [&](int jj0) {
    stK[0] = *reinterpret_cast<const uint4*>(Kg + (size_t)(jj0 + r0) * E_D + scc * 8);
    stK[1] = *reinterpret_cast<const uint4*>(Kg + (size_t)(jj0 + r1) * E_D + scc * 8);
    stV[0] = *reinterpret_cast<const uint4*>(Vg + (size_t)r0 * S_K + jj0 + scc * 8);
    stV[1] = *reinterpret_cast<const uint4*>(Vg + (size_t)r1 * S_K + jj0 + scc * 8);
  };
  auto LOAD_E = [&](int absrow0) {         // 64 rows
    stE[0] = *reinterpret_cast<const uint4*>(Ew + (size_t)(absrow0 + r0) * E_D + scc * 8);
    stE[1] = *reinterpret_cast<const uint4*>(Ew + (size_t)(absrow0 + r1) * E_D + scc * 8);
  };
  auto WRITE_KV = [&](int bb) {
    *reinterpret_cast<uint4*>(&Kls[bb][r0 * 64 + swc]) = stK[0];
    *reinterpret_cast<uint4*>(&Kls[bb][r1 * 64 + swc]) = stK[1];
    *reinterpret_cast<uint4*>(&Vls[bb][r0 * 64 + swc]) = stV[0];
    *reinterpret_cast<uint4*>(&Vls[bb][r1 * 64 + swc]) = stV[1];
  };
  auto WRITE_E = [&](int ringbase) {       // ringbase in {0,64,128}
    *reinterpret_cast<uint4*>(&Els[(ringbase + r0) * 64 + swc]) = stE[0];
    *reinterpret_cast<uint4*>(&Els[(ringbase + r1) * 64 + swc]) = stE[1];
  };

  // Q fragment (B operand): col=lo -> q-row iw+lo, k=hi*8+e (+32*kt)
  bf16x8 qa[2];
  {
    const u16* qrow = Qw + ((size_t)nh * L_Q + iw + lo) * E_D + hi * 8;
    qa[0] = *reinterpret_cast<const bf16x8*>(qrow);
    qa[1] = *reinterpret_cast<const bf16x8*>(qrow + 32);
  }

  // prologue: tile 0 K/V -> buf 0; E rows [Ebase, Ebase+128) -> slots 0,1
  LOAD_KV(0);          WRITE_KV(0);
  LOAD_E(Ebase);       WRITE_E(0);
  LOAD_E(Ebase + 64);  WRITE_E(64);
  if (nt > 1) { LOAD_KV(64); LOAD_E(Ebase + 128); }   // regs for iter 0's write
  __syncthreads();

  f32x4 o_acc[4] = {};
  float m_run = -1e30f, l_run = 0.f;
  const float* rb = &qe_lds[wid][lo * 80 + (15 - lo) + 4 * hi];
  const int lsw = lo & 7;
  int b = 0;
  int ering = 0;                           // ring base of tile t's first half
  f32x4 qe_carry = {};

  for (int t = 0; t < nt; ++t) {
    const int j0 = t * 64;

    // (1) write staged regs (K/V tile t+1 -> buf b^1; E rows 64(t+2) -> free slot)
    if (t + 1 < nt) {
      WRITE_KV(b ^ 1);
      WRITE_E((ering >= 64) ? (ering - 64) : (ering + 128));
    }
    // (2) issue loads for tile t+2
    if (t + 2 < nt) {
      LOAD_KV(j0 + 128);
      LOAD_E(Ebase + j0 + 192);
    }

    // (3) compute tile t from Kls[b], Vls[b], E ring slots {t, t+1}
    __builtin_amdgcn_s_setprio(1);
    f32x4 s_acc[4] = {};
#pragma unroll
    for (int kt = 0; kt < 2; ++kt)
#pragma unroll
      for (int ct = 0; ct < 4; ++ct) {
        const bf16x8 kf = *reinterpret_cast<const bf16x8*>(
            &Kls[b][(ct * 16 + lo) * 64 + (((kt * 4 + hi) ^ lsw) * 8)]);
        s_acc[ct] = __builtin_amdgcn_mfma_f32_16x16x32_bf16(kf, qa[kt], s_acc[ct], 0, 0, 0);
      }

    f32x4 qe_acc[5];
    {
      const int base_r = ering + 48 - 16 * wid;       // + tt*16 may wrap once
      int rtt[5];
#pragma unroll
      for (int tt = 0; tt < 5; ++tt) {
        int rr = base_r + tt * 16;
        rtt[tt] = (rr >= 192) ? rr - 192 : rr;        // mult of 16 -> +lo no wrap
      }
      if (t == 0) {
        f32x4 z = {};
        qe_acc[0] = z;
#pragma unroll
        for (int kt = 0; kt < 2; ++kt) {
          const bf16x8 ef = *reinterpret_cast<const bf16x8*>(
              &Els[(rtt[0] + lo) * 64 + (((kt * 4 + hi) ^ lsw) * 8)]);
          qe_acc[0] = __builtin_amdgcn_mfma_f32_16x16x32_bf16(ef, qa[kt], qe_acc[0], 0, 0, 0);
        }
      } else {
        qe_acc[0] = qe_carry;                          // tile t-1's last subtile == tile t's first
      }
#pragma unroll
      for (int tt = 1; tt < 5; ++tt) { f32x4 z = {}; qe_acc[tt] = z; }
#pragma unroll
      for (int kt = 0; kt < 2; ++kt)
#pragma unroll
        for (int tt = 1; tt < 5; ++tt) {
          const bf16x8 ef = *reinterpret_cast<const bf16x8*>(
              &Els[(rtt[tt] + lo) * 64 + (((kt * 4 + hi) ^ lsw) * 8)]);
          qe_acc[tt] = __builtin_amdgcn_mfma_f32_16x16x32_bf16(ef, qa[kt], qe_acc[tt], 0, 0, 0);
        }
      qe_carry = qe_acc[4];
    }
    __builtin_amdgcn_s_setprio(0);

    // ---- spill QE to per-wave LDS (f32, stride 80; R8-verified skew algebra) ----
#pragma unroll
    for (int tt = 0; tt < 5; ++tt)
      *reinterpret_cast<f32x4*>(&qe_lds[wid][lo * 80 + tt * 16 + 4 * hi]) = qe_acc[tt];

    float4 klv[4];
#pragma unroll
    for (int ct = 0; ct < 4; ++ct)
      klv[ct] = *reinterpret_cast<const float4*>(klq + j0 + ct * 16);

    // ---- logits: QK + rel (u = key - q + 15) + key_len*log2e; causal mask ----
    const bool maskt = (t == nt - 1);
    const int thr = iw + lo - j0 - 4 * hi;   // mask iff ct*16+g > thr
    float p[4][4];
#pragma unroll
    for (int ct = 0; ct < 4; ++ct) {
      const float k0 = klv[ct].x * LOG2E, k1 = klv[ct].y * LOG2E;
      const float k2 = klv[ct].z * LOG2E, k3 = klv[ct].w * LOG2E;
      p[ct][0] = s_acc[ct][0] + rb[ct * 16 + 0] + k0;
      p[ct][1] = s_acc[ct][1] + rb[ct * 16 + 1] + k1;
      p[ct][2] = s_acc[ct][2] + rb[ct * 16 + 2] + k2;
      p[ct][3] = s_acc[ct][3] + rb[ct * 16 + 3] + k3;
      if (maskt) {
#pragma unroll
        for (int g = 0; g < 4; ++g)
          if (ct * 16 + g > thr) p[ct][g] = -1e30f;
      }
    }

    // ---- online softmax (stats per q=lo, reduced across the 4 hi-groups) ----
    float a0 = fmaxf(fmaxf(p[0][0], p[0][1]), fmaxf(p[0][2], p[0][3]));
    float a1 = fmaxf(fmaxf(p[1][0], p[1][1]), fmaxf(p[1][2], p[1][3]));
    float a2 = fmaxf(fmaxf(p[2][0], p[2][1]), fmaxf(p[2][2], p[2][3]));
    float a3 = fmaxf(fmaxf(p[3][0], p[3][1]), fmaxf(p[3][2], p[3][3]));
    float tmax = fmaxf(fmaxf(a0, a1), fmaxf(a2, a3));
    tmax = fmaxf(tmax, __shfl_xor(tmax, 16));
    tmax = fmaxf(tmax, __shfl_xor(tmax, 32));
    const float mnew = fmaxf(m_run, tmax);
    const float alpha = exp2f(m_run - mnew);
#pragma unroll
    for (int ct = 0; ct < 4; ++ct)
#pragma unroll
      for (int g = 0; g < 4; ++g)
        p[ct][g] = exp2f(p[ct][g] - mnew);
    float s0 = (p[0][0] + p[0][1]) + (p[0][2] + p[0][3]);
    float s1 = (p[1][0] + p[1][1]) + (p[1][2] + p[1][3]);
    float s2 = (p[2][0] + p[2][1]) + (p[2][2] + p[2][3]);
    float s3 = (p[3][0] + p[3][1]) + (p[3][2] + p[3][3]);
    float rs = (s0 + s1) + (s2 + s3);
    rs += __shfl_xor(rs, 16);
    rs += __shfl_xor(rs, 32);
    l_run = l_run * alpha + rs;
    m_run = mnew;

#pragma unroll
    for (int dt = 0; dt < 4; ++dt) o_acc[dt] = o_acc[dt] * alpha;

    // ---- pack P to bf16 (k-perm: e<4 -> key 4hi+e; e>=4 -> key 16+4hi+e-4) ----
    uint4 w0, w1;
    w0.x = pk2(p[0][0], p[0][1]); w0.y = pk2(p[0][2], p[0][3]);
    w0.z = pk2(p[1][0], p[1][1]); w0.w = pk2(p[1][2], p[1][3]);
    w1.x = pk2(p[2][0], p[2][1]); w1.y = pk2(p[2][2], p[2][3]);
    w1.z = pk2(p[3][0], p[3][1]); w1.w = pk2(p[3][2], p[3][3]);
    const bf16x8 pb0 = __builtin_bit_cast(bf16x8, w0);
    const bf16x8 pb1 = __builtin_bit_cast(bf16x8, w1);

    // ---- PV from swizzled V^T LDS (same key mapping as R8) ----
    __builtin_amdgcn_s_setprio(1);
#pragma unroll
    for (int kt = 0; kt < 2; ++kt)
#pragma unroll
      for (int dt = 0; dt < 4; ++dt) {
        const int vrow = dt * 16 + lo;
        const int ch = kt * 4 + (hi >> 1);
        const uint2 va2 = *reinterpret_cast<const uint2*>(
            &Vls[b][vrow * 64 + ((ch ^ lsw) * 8) + (hi & 1) * 4]);
        const uint2 vb2 = *reinterpret_cast<const uint2*>(
            &Vls[b][vrow * 64 + (((ch + 2) ^ lsw) * 8) + (hi & 1) * 4]);
        uint4 uw; uw.x = va2.x; uw.y = va2.y; uw.z = vb2.x; uw.w = vb2.y;
        const bf16x8 vf = __builtin_bit_cast(bf16x8, uw);
        o_acc[dt] = __builtin_amdgcn_mfma_f32_16x16x32_bf16(vf, kt ? pb1 : pb0, o_acc[dt], 0, 0, 0);
      }
    __builtin_amdgcn_s_setprio(0);

    // (4) one barrier per tile
    __syncthreads();
    b ^= 1;
    ering = (ering == 128) ? 0 : (ering + 64);
  }

  // ---- epilogue ----
  const float inv = 1.f / l_run;
  float* ob = Op + (size_t)n * L_Q * RSTRIDE + h * E_D + (size_t)(iw + lo) * RSTRIDE;
#pragma unroll
  for (int dt = 0; dt < 4; ++dt) {
    f32x4 o = o_acc[dt] * inv;
    *reinterpret_cast<f32x4*>(ob + dt * 16 + 4 * hi) = o;
  }
}

// ---- fallback (no workspace): R3's verified non-packed kernel ----
__global__ __launch_bounds__(64, 2)
void relattn_fb(const float* __restrict__ Qf, const float* __restrict__ Kf,
                const float* __restrict__ Vf, const float* __restrict__ Ef,
                const float* __restrict__ KLp, float* __restrict__ Op) {
  const int bid = blockIdx.x;
  const int nh = bid & 15;
  const int n = nh >> 3, h = nh & 7;
  const int wq = 127 - (bid >> 4);
  const int iw = wq * 16;
  const int lane = threadIdx.x & 63;
  const int lo = lane & 15, hi = lane >> 4;

  __shared__ u16 p_lds[16 * 72];

  const float* klp = KLp + (size_t)n * S_K;
  float* ob = Op + (size_t)n * L_Q * RSTRIDE + h * E_D;

  bf16x8 qa[2];
  const float* qb = Qf + ((size_t)(n * L_Q + iw + lo) * N_H + h) * E_D + hi * 8;
  qa[0] = loadpack8(qb, 0.125f);
  qa[1] = loadpack8(qb + 32, 0.125f);

  f32x4 o_acc[4] = {};
  float m_run[4], l_run[4];
#pragma unroll
  for (int g = 0; g < 4; ++g) { m_run[g] = -1e30f; l_run[g] = 0.f; }

  const int ntiles = (wq >> 2) + 1;
  for (int t = 0; t < ntiles; ++t) {
    const int j0 = t * 64;
    f32x4 s_acc[4] = {};
#pragma unroll
    for (int kt = 0; kt < 2; ++kt)
#pragma unroll
      for (int ct = 0; ct < 4; ++ct) {
        bf16x8 kf = loadpack8(Kf + ((size_t)(n * S_K + j0 + ct * 16 + lo) * N_H + h) * E_D
                                  + kt * 32 + hi * 8, 1.f);
        s_acc[ct] = __builtin_amdgcn_mfma_f32_16x16x32_bf16(qa[kt], kf, s_acc[ct], 0, 0, 0);
      }
    const int mbase = (L_Q - 1) - (iw + 15) + j0;
    f32x4 qe_acc[5] = {};
#pragma unroll
    for (int kt = 0; kt < 2; ++kt)
#pragma unroll
      for (int tt = 0; tt < 5; ++tt) {
        int mr = mbase + tt * 16 + lo;
        mr = mr > (L_Q - 1) ? (L_Q - 1) : mr;
        bf16x8 ef = loadpack8(Ef + (size_t)mr * E_D + kt * 32 + hi * 8, 1.f);
        qe_acc[tt] = __builtin_amdgcn_mfma_f32_16x16x32_bf16(qa[kt], ef, qe_acc[tt], 0, 0, 0);
      }
    float kladd[4];
#pragma unroll
    for (int ct = 0; ct < 4; ++ct) kladd[ct] = klp[j0 + ct * 16 + lo];
    float sv[4][4];
#pragma unroll
    for (int ct = 0; ct < 4; ++ct) {
      const int jj = ct * 16 + lo;
#pragma unroll
      for (int g = 0; g < 4; ++g) {
        const int r = 4 * hi + g;
        const int u = jj - r + 15;
        const int srcl = (u & 15) | (hi << 4);
        const float a = __shfl(qe_acc[ct][g], srcl);
        const float bq = __shfl(qe_acc[ct + 1][g], srcl);
        const float rel = (lo <= r) ? a : bq;
        float s = s_acc[ct][g] + rel + kladd[ct];
        if (j0 + jj > iw + r) s = -1e9f;
        sv[ct][g] = s;
      }
    }
    float alpha[4];
#pragma unroll
    for (int g = 0; g < 4; ++g) {
      float mx = fmaxf(fmaxf(sv[0][g], sv[1][g]), fmaxf(sv[2][g], sv[3][g]));
      mx = fmaxf(mx, __shfl_xor(mx, 1));
      mx = fmaxf(mx, __shfl_xor(mx, 2));
      mx = fmaxf(mx, __shfl_xor(mx, 4));
      mx = fmaxf(mx, __shfl_xor(mx, 8));
      const float mnew = fmaxf(m_run[g], mx);
      const float al = __expf(m_run[g] - mnew);
      float rsv = 0.f;
#pragma unroll
      for (int ct = 0; ct < 4; ++ct) {
        const float pv = __expf(sv[ct][g] - mnew);
        sv[ct][g] = pv;
        rsv += pv;
      }
      rsv += __shfl_xor(rsv, 1);
      rsv += __shfl_xor(rsv, 2);
      rsv += __shfl_xor(rsv, 4);
      rsv += __shfl_xor(rsv, 8);
      l_run[g] = l_run[g] * al + rsv;
      m_run[g] = mnew;
      alpha[g] = al;
    }
#pragma unroll
    for (int dt = 0; dt < 4; ++dt)
#pragma unroll
      for (int g = 0; g < 4; ++g)
        o_acc[dt][g] *= alpha[g];
#pragma unroll
    for (int ct = 0; ct < 4; ++ct)
#pragma unroll
      for (int g = 0; g < 4; ++g)
        p_lds[(4 * hi + g) * 72 + ct * 16 + lo] = (u16)f2bf(sv[ct][g]);
#pragma unroll
    for (int jt = 0; jt < 2; ++jt) {
      const bf16x8 pav = *reinterpret_cast<const bf16x8*>(&p_lds[lo * 72 + jt * 32 + hi * 8]);
#pragma unroll
      for (int dt = 0; dt < 4; ++dt) {
        bf16x8 vf;
        const float* vp = Vf + ((size_t)(n * S_K + j0 + jt * 32 + hi * 8) * N_H + h) * E_D
                            + dt * 16 + lo;
#pragma unroll
        for (int e = 0; e < 8; ++e) vf[e] = f2bf(vp[(size_t)e * RSTRIDE]);
        o_acc[dt] = __builtin_amdgcn_mfma_f32_16x16x32_bf16(pav, vf, o_acc[dt], 0, 0, 0);
      }
    }
  }
  float inv[4];
#pragma unroll
  for (int g = 0; g < 4; ++g) inv[g] = 1.f / l_run[g];
#pragma unroll
  for (int dt = 0; dt < 4; ++dt)
#pragma unroll
    for (int g = 0; g < 4; ++g)
      ob[(size_t)(iw + 4 * hi + g) * RSTRIDE + dt * 16 + lo] = o_acc[dt][g] * inv[g];
}

extern "C" void kernel_launch(void* const* d_in, const int* in_sizes, int n_in,
                              void* d_out, int out_size, void* d_ws, size_t ws_size,
                              hipStream_t stream) {
  const float* Q  = (const float*)d_in[0];
  const float* K  = (const float*)d_in[1];
  const float* V  = (const float*)d_in[2];
  const float* E  = (const float*)d_in[3];
  // d_in[4] = attn_mask_add: exactly the causal 0/-1e9 mask -> applied structurally
  const float* KL = (const float*)d_in[5];
  float* O = (float*)d_out;

  char* ws = (char*)d_ws;
  u16* Qw   = (u16*)(ws + QW_OFF);
  u16* Kw   = (u16*)(ws + KW_OFF);
  u16* Vtw  = (u16*)(ws + VT_OFF);
  u16* Ew   = (u16*)(ws + EW_OFF);

  if (ws_size >= WS_PACK) {
    hipLaunchKernelGGL(pack_qke, dim3((1048576 + 32768 + 255) / 256), dim3(256), 0, stream,
                       Q, K, E, Qw, Kw, Ew);
    hipLaunchKernelGGL(pack_vt, dim3(32, 16), dim3(256), 0, stream, V, Vtw);
    hipLaunchKernelGGL(relattn_r9, dim3(512), dim3(256), 0, stream,
                       Qw, Kw, Vtw, Ew, KL, O);
  } else {
    hipLaunchKernelGGL(relattn_fb, dim3(2048), dim3(64), 0, stream, Q, K, V, E, KL, O);
  }
}

// Round 11
// 93.567 us; speedup vs baseline: 1.7505x; 1.1467x over previous
//
#include <hip/hip_runtime.h>
#include <hip/hip_bf16.h>

// Relative (Music-Transformer) causal attention, MI355X gfx950.
// logit[i,j] = q_i·k_j + q_i·Erel[L-1-i+j] + key_len_add[j]; causal softmax; ·V
// fp32 in / fp32 out. Swapped-operand 16x16x32 bf16 MFMA ([key][q] layout).
// R11 = R10 with the QE-spill stride fixed 76 -> 80 (stride must cover the
// 80-value u-band; 76 aliased adjacent q-columns and wrote OOB -> NaN).

typedef __attribute__((ext_vector_type(8))) short bf16x8;
typedef __attribute__((ext_vector_type(4))) float f32x4;
typedef unsigned short u16;

#define L_Q 2048
#define S_K 2048
#define N_H 8
#define E_D 64
#define RSTRIDE 512
#define LOG2E 1.44269504088896f

#define QW_OFF 0u
#define KW_OFF (4u << 20)
#define VT_OFF (8u << 20)
#define EW_OFF (12u << 20)            // 1MB region; rows >=2048 unwritten -> masked slots only
#define ML_OFF (13u << 20)            // 1024 splits x 128 f32 = 512 KB
#define OW_OFF ((13u << 20) + (512u << 10))
#define WS_PACK ((size_t)(13u << 20))
#define WS_FULL ((size_t)OW_OFF + (size_t)1024 * 4096 * 4)   // ~30.9 MB (R4 proved >=31.4 MB exists)

static __device__ __forceinline__ short f2bf(float f) {
  unsigned u = __builtin_bit_cast(unsigned, f);
  u += 0x7fffu + ((u >> 16) & 1u);   // RNE
  return (short)(u >> 16);
}

static __device__ __forceinline__ unsigned pk2(float a, float b) {
  return (unsigned)(u16)f2bf(a) | ((unsigned)(u16)f2bf(b) << 16);
}

static __device__ __forceinline__ bf16x8 loadpack8(const float* __restrict__ p, float scale) {
  float4 a = *reinterpret_cast<const float4*>(p);
  float4 b = *reinterpret_cast<const float4*>(p + 4);
  bf16x8 r;
  r[0] = f2bf(a.x * scale); r[1] = f2bf(a.y * scale);
  r[2] = f2bf(a.z * scale); r[3] = f2bf(a.w * scale);
  r[4] = f2bf(b.x * scale); r[5] = f2bf(b.y * scale);
  r[6] = f2bf(b.z * scale); r[7] = f2bf(b.w * scale);
  return r;
}

// ---- prep: Q (scaled by 1/8*log2e) & K -> bf16 [nh][seq][e]; Erel -> bf16 ----
__global__ __launch_bounds__(256)
void pack_qke(const float* __restrict__ Qf, const float* __restrict__ Kf,
              const float* __restrict__ Ef, u16* __restrict__ Qw,
              u16* __restrict__ Kw, u16* __restrict__ Ew) {
  const unsigned u = blockIdx.x * 256 + threadIdx.x;   // one float4 per thread
  if (u < 1048576u) {
    const unsigned v  = u & 524287u;
    const int e  = (v & 15) * 4;
    const int i  = (v >> 4) & 2047;
    const int nh = v >> 15;
    const int n = nh >> 3, h = nh & 7;
    const size_t src = ((size_t)(n * L_Q + i) * N_H + h) * E_D + e;
    const size_t dst = ((size_t)nh * L_Q + i) * E_D + e;
    const bool isQ = u < 524288u;
    float4 x = *reinterpret_cast<const float4*>((isQ ? Qf : Kf) + src);
    const float s = isQ ? 0.125f * LOG2E : 1.0f;
    ushort4 o;
    o.x = (u16)f2bf(x.x * s); o.y = (u16)f2bf(x.y * s);
    o.z = (u16)f2bf(x.z * s); o.w = (u16)f2bf(x.w * s);
    *reinterpret_cast<ushort4*>((isQ ? Qw : Kw) + dst) = o;
  } else {
    const unsigned v = u - 1048576u;                    // Erel
    if (v < 32768u) {
      const size_t idx = (size_t)v * 4;
      float4 x = *reinterpret_cast<const float4*>(Ef + idx);
      ushort4 o;
      o.x = (u16)f2bf(x.x); o.y = (u16)f2bf(x.y);
      o.z = (u16)f2bf(x.z); o.w = (u16)f2bf(x.w);
      *reinterpret_cast<ushort4*>(Ew + idx) = o;
    }
  }
}

// ---- prep: V -> bf16 transposed [nh][d][j] ----
__global__ __launch_bounds__(256)
void pack_vt(const float* __restrict__ Vf, u16* __restrict__ Vtw) {
  __shared__ u16 t[64][72];
  const int j0 = blockIdx.x * 64;
  const int nh = blockIdx.y;
  const int n = nh >> 3, h = nh & 7;
  const int tid = threadIdx.x;
  {
    const int jr = tid >> 2, dg = (tid & 3) * 16;
    const float* src = Vf + ((size_t)(n * L_Q + j0 + jr) * N_H + h) * E_D + dg;
#pragma unroll
    for (int q = 0; q < 4; ++q) {
      float4 x = *reinterpret_cast<const float4*>(src + q * 4);
      t[jr][dg + q * 4 + 0] = (u16)f2bf(x.x);
      t[jr][dg + q * 4 + 1] = (u16)f2bf(x.y);
      t[jr][dg + q * 4 + 2] = (u16)f2bf(x.z);
      t[jr][dg + q * 4 + 3] = (u16)f2bf(x.w);
    }
  }
  __syncthreads();
  {
    const int dr = tid >> 2, jg = (tid & 3) * 16;
    u16 tmp[16];
#pragma unroll
    for (int jj = 0; jj < 16; ++jj) tmp[jj] = t[jg + jj][dr];
    u16* dst = Vtw + ((size_t)nh * E_D + dr) * S_K + j0 + jg;
    *reinterpret_cast<uint4*>(dst)     = *reinterpret_cast<uint4*>(&tmp[0]);
    *reinterpret_cast<uint4*>(dst + 8) = *reinterpret_cast<uint4*>(&tmp[8]);
  }
}

// ---- main: K/V shared LDS dbuf; E direct; optional KV-split x2 ----
template <bool SPLIT>
__global__ __launch_bounds__(256, 3)
void relattn_r11(const u16* __restrict__ Qw, const u16* __restrict__ Kw,
                 const u16* __restrict__ Vtw, const u16* __restrict__ Ew,
                 const float* __restrict__ KLp, float* __restrict__ Op,
                 float* __restrict__ OwP, float* __restrict__ MLp) {
  const int bid = blockIdx.x;
  const int nh = bid & 15;                 // head -> fixed XCD pattern
  const int n = nh >> 3, h = nh & 7;
  const int rest = bid >> 4;
  const int wq64 = SPLIT ? (31 - (rest >> 1))
                         : ((rest < 16) ? (31 - rest) : (rest - 16));
  const int sp = SPLIT ? (rest & 1) : 0;
  const int iw64 = wq64 * 64;
  const int tid = threadIdx.x;
  const int wid = tid >> 6;
  const int lane = tid & 63;
  const int lo = lane & 15, hi = lane >> 4;
  const int iw = iw64 + wid * 16;          // this wave's first q-row
  const int nt = wq64 + 1;
  const int t0 = (SPLIT && sp) ? (nt >> 1) : 0;
  const int t1 = (SPLIT && !sp) ? (nt >> 1) : nt;
  const int s = (wq64 * 16 + nh) * 2 + sp;

  __shared__ u16 Kls[2][64 * 64];          // K tiles, swizzled (chunk ^= row&7)
  __shared__ u16 Vls[2][64 * 64];          // V^T tiles, swizzled
  __shared__ float qe_lds[4][16 * 80];     // per-wave QE spill, stride 80 (u-band is 80 wide!)

  if (SPLIT && t0 >= t1) {                 // empty split: neutral partials
    f32x4 z = {};
    f32x4* OwF = reinterpret_cast<f32x4*>(OwP) + (size_t)s * 1024 + wid * 256 + lane;
#pragma unroll
    for (int dt = 0; dt < 4; ++dt) OwF[dt * 64] = z;
    if (lane < 16) {
      MLp[s * 128 + wid * 32 + lane] = -1e30f;
      MLp[s * 128 + wid * 32 + 16 + lane] = 0.f;
    }
    return;
  }

  const u16* Kg = Kw + (size_t)nh * S_K * E_D;
  const u16* Vg = Vtw + (size_t)nh * E_D * S_K;
  const float* klq = KLp + (size_t)n * S_K + 4 * hi;
  // E direct-global per-lane base (R6-verified): row = 2032 - iw + j0 + tt*16 + lo
  const u16* epl = Ew + (size_t)(2032 - iw) * E_D + lo * E_D + hi * 8;

  // staging lane coords
  const int srow = lane >> 3;
  const int scc  = lane & 7;
  const int r0 = wid * 8 + srow;           // 0..31
  const int r1 = r0 + 32;                  // 32..63
  const int swc = (scc ^ srow) * 8;        // swizzled 16B-chunk offset (u16 units)
  uint4 stK[2], stV[2];

  auto LOAD_KV = [&](int jj0) {
    stK[0] = *reinterpret_cast<const uint4*>(Kg + (size_t)(jj0 + r0) * E_D + scc * 8);
    stK[1] = *reinterpret_cast<const uint4*>(Kg + (size_t)(jj0 + r1) * E_D + scc * 8);
    stV[0] = *reinterpret_cast<const uint4*>(Vg + (size_t)r0 * S_K + jj0 + scc * 8);
    stV[1] = *reinterpret_cast<const uint4*>(Vg + (size_t)r1 * S_K + jj0 + scc * 8);
  };
  auto WRITE_KV = [&](int bb) {
    *reinterpret_cast<uint4*>(&Kls[bb][r0 * 64 + swc]) = stK[0];
    *reinterpret_cast<uint4*>(&Kls[bb][r1 * 64 + swc]) = stK[1];
    *reinterpret_cast<uint4*>(&Vls[bb][r0 * 64 + swc]) = stV[0];
    *reinterpret_cast<uint4*>(&Vls[bb][r1 * 64 + swc]) = stV[1];
  };

  bf16x8 efc[8];                           // next-tile E subtiles 1..4 x kt
  auto LOAD_EFC = [&](int tt64) {
#pragma unroll
    for (int kt = 0; kt < 2; ++kt)
#pragma unroll
      for (int tt = 1; tt < 5; ++tt)
        efc[kt * 4 + tt - 1] = *reinterpret_cast<const bf16x8*>(
            epl + (size_t)(tt64 * 64 + tt * 16) * E_D + kt * 32);
  };

  // Q fragment (B operand): col=lo -> q-row iw+lo, k=hi*8+e (+32*kt)
  bf16x8 qa[2];
  {
    const u16* qrow = Qw + ((size_t)nh * L_Q + iw + lo) * E_D + hi * 8;
    qa[0] = *reinterpret_cast<const bf16x8*>(qrow);
    qa[1] = *reinterpret_cast<const bf16x8*>(qrow + 32);
  }

  // prologue
  LOAD_KV(t0 * 64);
  WRITE_KV(0);
  if (t0 + 1 < t1) LOAD_KV((t0 + 1) * 64);
  LOAD_EFC(t0);
  __syncthreads();

  f32x4 o_acc[4] = {};
  float m_run = -1e30f, l_run = 0.f;
  const float* rb = &qe_lds[wid][lo * 80 + (15 - lo) + 4 * hi];
  const int lsw = lo & 7;
  int b = 0;
  f32x4 qe_carry = {};

  for (int t = t0; t < t1; ++t) {
    const int j0 = t * 64;
    if (t + 1 < t1) WRITE_KV(b ^ 1);
    if (t + 2 < t1) LOAD_KV(j0 + 128);

    // ---- QK^T from swizzled LDS ----
    __builtin_amdgcn_s_setprio(1);
    f32x4 s_acc[4] = {};
#pragma unroll
    for (int kt = 0; kt < 2; ++kt)
#pragma unroll
      for (int ct = 0; ct < 4; ++ct) {
        const bf16x8 kf = *reinterpret_cast<const bf16x8*>(
            &Kls[b][(ct * 16 + lo) * 64 + (((kt * 4 + hi) ^ lsw) * 8)]);
        s_acc[ct] = __builtin_amdgcn_mfma_f32_16x16x32_bf16(kf, qa[kt], s_acc[ct], 0, 0, 0);
      }

    // ---- QE band: subtile 0 = carry (or fresh at t0); 1..4 from prefetched efc ----
    f32x4 qe_acc[5];
    if (t == t0) {
      f32x4 z = {};
      qe_acc[0] = z;
#pragma unroll
      for (int kt = 0; kt < 2; ++kt) {
        const bf16x8 e0 = *reinterpret_cast<const bf16x8*>(
            epl + (size_t)(t0 * 64) * E_D + kt * 32);
        qe_acc[0] = __builtin_amdgcn_mfma_f32_16x16x32_bf16(e0, qa[kt], qe_acc[0], 0, 0, 0);
      }
    } else {
      qe_acc[0] = qe_carry;
    }
#pragma unroll
    for (int tt = 1; tt < 5; ++tt) { f32x4 z = {}; qe_acc[tt] = z; }
#pragma unroll
    for (int kt = 0; kt < 2; ++kt)
#pragma unroll
      for (int tt = 1; tt < 5; ++tt)
        qe_acc[tt] = __builtin_amdgcn_mfma_f32_16x16x32_bf16(efc[kt * 4 + tt - 1], qa[kt],
                                                             qe_acc[tt], 0, 0, 0);
    qe_carry = qe_acc[4];
    __builtin_amdgcn_s_setprio(0);

    if (t + 1 < t1) LOAD_EFC(t + 1);       // prefetch next tile's E (latency hidden)

    // ---- spill QE to per-wave LDS (f32, stride 80) ----
#pragma unroll
    for (int tt = 0; tt < 5; ++tt)
      *reinterpret_cast<f32x4*>(&qe_lds[wid][lo * 80 + tt * 16 + 4 * hi]) = qe_acc[tt];

    float4 klv[4];
#pragma unroll
    for (int ct = 0; ct < 4; ++ct)
      klv[ct] = *reinterpret_cast<const float4*>(klq + j0 + ct * 16);

    // ---- logits: QK + rel (u = key - q + 15) + key_len*log2e; causal mask ----
    const bool maskt = (t == nt - 1);
    const int thr = iw + lo - j0 - 4 * hi;   // mask iff ct*16+g > thr
    float p[4][4];
#pragma unroll
    for (int ct = 0; ct < 4; ++ct) {
      const float k0 = klv[ct].x * LOG2E, k1 = klv[ct].y * LOG2E;
      const float k2 = klv[ct].z * LOG2E, k3 = klv[ct].w * LOG2E;
      p[ct][0] = s_acc[ct][0] + rb[ct * 16 + 0] + k0;
      p[ct][1] = s_acc[ct][1] + rb[ct * 16 + 1] + k1;
      p[ct][2] = s_acc[ct][2] + rb[ct * 16 + 2] + k2;
      p[ct][3] = s_acc[ct][3] + rb[ct * 16 + 3] + k3;
      if (maskt) {
#pragma unroll
        for (int g = 0; g < 4; ++g)
          if (ct * 16 + g > thr) p[ct][g] = -1e30f;
      }
    }

    // ---- online softmax (stats per q=lo, reduced across the 4 hi-groups) ----
    float a0 = fmaxf(fmaxf(p[0][0], p[0][1]), fmaxf(p[0][2], p[0][3]));
    float a1 = fmaxf(fmaxf(p[1][0], p[1][1]), fmaxf(p[1][2], p[1][3]));
    float a2 = fmaxf(fmaxf(p[2][0], p[2][1]), fmaxf(p[2][2], p[2][3]));
    float a3 = fmaxf(fmaxf(p[3][0], p[3][1]), fmaxf(p[3][2], p[3][3]));
    float tmax = fmaxf(fmaxf(a0, a1), fmaxf(a2, a3));
    tmax = fmaxf(tmax, __shfl_xor(tmax, 16));
    tmax = fmaxf(tmax, __shfl_xor(tmax, 32));
    const float mnew = fmaxf(m_run, tmax);
    const float alpha = exp2f(m_run - mnew);
#pragma unroll
    for (int ct = 0; ct < 4; ++ct)
#pragma unroll
      for (int g = 0; g < 4; ++g)
        p[ct][g] = exp2f(p[ct][g] - mnew);
    float s0 = (p[0][0] + p[0][1]) + (p[0][2] + p[0][3]);
    float s1 = (p[1][0] + p[1][1]) + (p[1][2] + p[1][3]);
    float s2 = (p[2][0] + p[2][1]) + (p[2][2] + p[2][3]);
    float s3 = (p[3][0] + p[3][1]) + (p[3][2] + p[3][3]);
    float rs = (s0 + s1) + (s2 + s3);
    rs += __shfl_xor(rs, 16);
    rs += __shfl_xor(rs, 32);
    l_run = l_run * alpha + rs;
    m_run = mnew;

#pragma unroll
    for (int dt = 0; dt < 4; ++dt) o_acc[dt] = o_acc[dt] * alpha;

    // ---- pack P to bf16 (k-perm: e<4 -> key 4hi+e; e>=4 -> key 16+4hi+e-4) ----
    uint4 w0, w1;
    w0.x = pk2(p[0][0], p[0][1]); w0.y = pk2(p[0][2], p[0][3]);
    w0.z = pk2(p[1][0], p[1][1]); w0.w = pk2(p[1][2], p[1][3]);
    w1.x = pk2(p[2][0], p[2][1]); w1.y = pk2(p[2][2], p[2][3]);
    w1.z = pk2(p[3][0], p[3][1]); w1.w = pk2(p[3][2], p[3][3]);
    const bf16x8 pb0 = __builtin_bit_cast(bf16x8, w0);
    const bf16x8 pb1 = __builtin_bit_cast(bf16x8, w1);

    // ---- PV from swizzled V^T LDS ----
    __builtin_amdgcn_s_setprio(1);
#pragma unroll
    for (int kt = 0; kt < 2; ++kt)
#pragma unroll
      for (int dt = 0; dt < 4; ++dt) {
        const int vrow = dt * 16 + lo;
        const int ch = kt * 4 + (hi >> 1);
        const uint2 va2 = *reinterpret_cast<const uint2*>(
            &Vls[b][vrow * 64 + ((ch ^ lsw) * 8) + (hi & 1) * 4]);
        const uint2 vb2 = *reinterpret_cast<const uint2*>(
            &Vls[b][vrow * 64 + (((ch + 2) ^ lsw) * 8) + (hi & 1) * 4]);
        uint4 uw; uw.x = va2.x; uw.y = va2.y; uw.z = vb2.x; uw.w = vb2.y;
        const bf16x8 vf = __builtin_bit_cast(bf16x8, uw);
        o_acc[dt] = __builtin_amdgcn_mfma_f32_16x16x32_bf16(vf, kt ? pb1 : pb0, o_acc[dt], 0, 0, 0);
      }
    __builtin_amdgcn_s_setprio(0);

    __syncthreads();
    b ^= 1;
  }

  // ---- epilogue ----
  if (SPLIT) {
    f32x4* OwF = reinterpret_cast<f32x4*>(OwP) + (size_t)s * 1024 + wid * 256 + lane;
#pragma unroll
    for (int dt = 0; dt < 4; ++dt) OwF[dt * 64] = o_acc[dt];
    if (lane < 16) {
      MLp[s * 128 + wid * 32 + lane] = m_run;
      MLp[s * 128 + wid * 32 + 16 + lane] = l_run;
    }
  } else {
    const float inv = 1.f / l_run;
    float* ob = Op + (size_t)n * L_Q * RSTRIDE + h * E_D + (size_t)(iw + lo) * RSTRIDE;
#pragma unroll
    for (int dt = 0; dt < 4; ++dt) {
      f32x4 o = o_acc[dt] * inv;
      *reinterpret_cast<f32x4*>(ob + dt * 16 + 4 * hi) = o;
    }
  }
}

// ---- combine the two KV-split partials (64 q-rows per block) ----
__global__ __launch_bounds__(256)
void combine64(const float* __restrict__ OwP, const float* __restrict__ MLp,
               float* __restrict__ Op) {
  const int pair = blockIdx.x;             // wq64*16 + nh, 512 blocks
  const int nh = pair & 15;
  const int wq64 = pair >> 4;
  const int n = nh >> 3, h = nh & 7;
  const int tid = threadIdx.x;
  const int wid = tid >> 6;
  const int lane = tid & 63;
  const int lo = lane & 15, hi = lane >> 4;
  const int s0 = pair * 2, s1 = s0 + 1;
  const float m0 = MLp[s0 * 128 + wid * 32 + lo], l0 = MLp[s0 * 128 + wid * 32 + 16 + lo];
  const float m1 = MLp[s1 * 128 + wid * 32 + lo], l1 = MLp[s1 * 128 + wid * 32 + 16 + lo];
  const float M  = fmaxf(m0, m1);
  const float w0 = exp2f(m0 - M), w1 = exp2f(m1 - M);
  const float inv = 1.f / (l0 * w0 + l1 * w1);
  const f32x4* A = reinterpret_cast<const f32x4*>(OwP) + (size_t)s0 * 1024 + wid * 256 + lane;
  const f32x4* B = reinterpret_cast<const f32x4*>(OwP) + (size_t)s1 * 1024 + wid * 256 + lane;
  float* ob = Op + (size_t)n * L_Q * RSTRIDE + h * E_D
            + (size_t)(wq64 * 64 + wid * 16 + lo) * RSTRIDE;
#pragma unroll
  for (int dt = 0; dt < 4; ++dt) {
    f32x4 o = (A[dt * 64] * w0 + B[dt * 64] * w1) * inv;
    *reinterpret_cast<f32x4*>(ob + dt * 16 + 4 * hi) = o;
  }
}

// ---- fallback (no workspace): R3's verified non-packed kernel ----
__global__ __launch_bounds__(64, 2)
void relattn_fb(const float* __restrict__ Qf, const float* __restrict__ Kf,
                const float* __restrict__ Vf, const float* __restrict__ Ef,
                const float* __restrict__ KLp, float* __restrict__ Op) {
  const int bid = blockIdx.x;
  const int nh = bid & 15;
  const int n = nh >> 3, h = nh & 7;
  const int wq = 127 - (bid >> 4);
  const int iw = wq * 16;
  const int lane = threadIdx.x & 63;
  const int lo = lane & 15, hi = lane >> 4;

  __shared__ u16 p_lds[16 * 72];

  const float* klp = KLp + (size_t)n * S_K;
  float* ob = Op + (size_t)n * L_Q * RSTRIDE + h * E_D;

  bf16x8 qa[2];
  const float* qb = Qf + ((size_t)(n * L_Q + iw + lo) * N_H + h) * E_D + hi * 8;
  qa[0] = loadpack8(qb, 0.125f);
  qa[1] = loadpack8(qb + 32, 0.125f);

  f32x4 o_acc[4] = {};
  float m_run[4], l_run[4];
#pragma unroll
  for (int g = 0; g < 4; ++g) { m_run[g] = -1e30f; l_run[g] = 0.f; }

  const int ntiles = (wq >> 2) + 1;
  for (int t = 0; t < ntiles; ++t) {
    const int j0 = t * 64;
    f32x4 s_acc[4] = {};
#pragma unroll
    for (int kt = 0; kt < 2; ++kt)
#pragma unroll
      for (int ct = 0; ct < 4; ++ct) {
        bf16x8 kf = loadpack8(Kf + ((size_t)(n * S_K + j0 + ct * 16 + lo) * N_H + h) * E_D
                                  + kt * 32 + hi * 8, 1.f);
        s_acc[ct] = __builtin_amdgcn_mfma_f32_16x16x32_bf16(qa[kt], kf, s_acc[ct], 0, 0, 0);
      }
    const int mbase = (L_Q - 1) - (iw + 15) + j0;
    f32x4 qe_acc[5] = {};
#pragma unroll
    for (int kt = 0; kt < 2; ++kt)
#pragma unroll
      for (int tt = 0; tt < 5; ++tt) {
        int mr = mbase + tt * 16 + lo;
        mr = mr > (L_Q - 1) ? (L_Q - 1) : mr;
        bf16x8 ef = loadpack8(Ef + (size_t)mr * E_D + kt * 32 + hi * 8, 1.f);
        qe_acc[tt] = __builtin_amdgcn_mfma_f32_16x16x32_bf16(qa[kt], ef, qe_acc[tt], 0, 0, 0);
      }
    float kladd[4];
#pragma unroll
    for (int ct = 0; ct < 4; ++ct) kladd[ct] = klp[j0 + ct * 16 + lo];
    float sv[4][4];
#pragma unroll
    for (int ct = 0; ct < 4; ++ct) {
      const int jj = ct * 16 + lo;
#pragma unroll
      for (int g = 0; g < 4; ++g) {
        const int r = 4 * hi + g;
        const int u = jj - r + 15;
        const int srcl = (u & 15) | (hi << 4);
        const float a = __shfl(qe_acc[ct][g], srcl);
        const float bq = __shfl(qe_acc[ct + 1][g], srcl);
        const float rel = (lo <= r) ? a : bq;
        float sv2 = s_acc[ct][g] + rel + kladd[ct];
        if (j0 + jj > iw + r) sv2 = -1e9f;
        sv[ct][g] = sv2;
      }
    }
    float alpha[4];
#pragma unroll
    for (int g = 0; g < 4; ++g) {
      float mx = fmaxf(fmaxf(sv[0][g], sv[1][g]), fmaxf(sv[2][g], sv[3][g]));
      mx = fmaxf(mx, __shfl_xor(mx, 1));
      mx = fmaxf(mx, __shfl_xor(mx, 2));
      mx = fmaxf(mx, __shfl_xor(mx, 4));
      mx = fmaxf(mx, __shfl_xor(mx, 8));
      const float mnew = fmaxf(m_run[g], mx);
      const float al = __expf(m_run[g] - mnew);
      float rsv = 0.f;
#pragma unroll
      for (int ct = 0; ct < 4; ++ct) {
        const float pv = __expf(sv[ct][g] - mnew);
        sv[ct][g] = pv;
        rsv += pv;
      }
      rsv += __shfl_xor(rsv, 1);
      rsv += __shfl_xor(rsv, 2);
      rsv += __shfl_xor(rsv, 4);
      rsv += __shfl_xor(rsv, 8);
      l_run[g] = l_run[g] * al + rsv;
      m_run[g] = mnew;
      alpha[g] = al;
    }
#pragma unroll
    for (int dt = 0; dt < 4; ++dt)
#pragma unroll
      for (int g = 0; g < 4; ++g)
        o_acc[dt][g] *= alpha[g];
#pragma unroll
    for (int ct = 0; ct < 4; ++ct)
#pragma unroll
      for (int g = 0; g < 4; ++g)
        p_lds[(4 * hi + g) * 72 + ct * 16 + lo] = (u16)f2bf(sv[ct][g]);
#pragma unroll
    for (int jt = 0; jt < 2; ++jt) {
      const bf16x8 pav = *reinterpret_cast<const bf16x8*>(&p_lds[lo * 72 + jt * 32 + hi * 8]);
#pragma unroll
      for (int dt = 0; dt < 4; ++dt) {
        bf16x8 vf;
        const float* vp = Vf + ((size_t)(n * S_K + j0 + jt * 32 + hi * 8) * N_H + h) * E_D
                            + dt * 16 + lo;
#pragma unroll
        for (int e = 0; e < 8; ++e) vf[e] = f2bf(vp[(size_t)e * RSTRIDE]);
        o_acc[dt] = __builtin_amdgcn_mfma_f32_16x16x32_bf16(pav, vf, o_acc[dt], 0, 0, 0);
      }
    }
  }
  float inv[4];
#pragma unroll
  for (int g = 0; g < 4; ++g) inv[g] = 1.f / l_run[g];
#pragma unroll
  for (int dt = 0; dt < 4; ++dt)
#pragma unroll
    for (int g = 0; g < 4; ++g)
      ob[(size_t)(iw + 4 * hi + g) * RSTRIDE + dt * 16 + lo] = o_acc[dt][g] * inv[g];
}

extern "C" void kernel_launch(void* const* d_in, const int* in_sizes, int n_in,
                              void* d_out, int out_size, void* d_ws, size_t ws_size,
                              hipStream_t stream) {
  const float* Q  = (const float*)d_in[0];
  const float* K  = (const float*)d_in[1];
  const float* V  = (const float*)d_in[2];
  const float* E  = (const float*)d_in[3];
  // d_in[4] = attn_mask_add: exactly the causal 0/-1e9 mask -> applied structurally
  const float* KL = (const float*)d_in[5];
  float* O = (float*)d_out;

  char* ws = (char*)d_ws;
  u16* Qw   = (u16*)(ws + QW_OFF);
  u16* Kw   = (u16*)(ws + KW_OFF);
  u16* Vtw  = (u16*)(ws + VT_OFF);
  u16* Ew   = (u16*)(ws + EW_OFF);
  float* ML = (float*)(ws + ML_OFF);
  float* Ow = (float*)(ws + OW_OFF);

  const bool ws_pack = ws_size >= WS_PACK;
  const bool ws_full = ws_size >= WS_FULL;

  if (ws_pack) {
    hipLaunchKernelGGL(pack_qke, dim3((1048576 + 32768 + 255) / 256), dim3(256), 0, stream,
                       Q, K, E, Qw, Kw, Ew);
    hipLaunchKernelGGL(pack_vt, dim3(32, 16), dim3(256), 0, stream, V, Vtw);
  }
  if (ws_full) {
    hipLaunchKernelGGL((relattn_r11<true>), dim3(1024), dim3(256), 0, stream,
                       Qw, Kw, Vtw, Ew, KL, O, Ow, ML);
    hipLaunchKernelGGL(combine64, dim3(512), dim3(256), 0, stream, Ow, ML, O);
  } else if (ws_pack) {
    hipLaunchKernelGGL((relattn_r11<false>), dim3(512), dim3(256), 0, stream,
                       Qw, Kw, Vtw, Ew, KL, O, Ow, ML);
  } else {
    hipLaunchKernelGGL(relattn_fb, dim3(2048), dim3(64), 0, stream, Q, K, V, E, KL, O);
  }
}